// Round 1
// baseline (476.424 us; speedup 1.0000x reference)
//
#include <hip/hip_runtime.h>
#include <cstdint>
#include <cstddef>

typedef short bf16x8 __attribute__((ext_vector_type(8)));
typedef float f32x4  __attribute__((ext_vector_type(4)));
typedef unsigned short u16;

#define DEVI __device__ __forceinline__

constexpr int C     = 192;
constexpr int HEADS = 6;
constexpr int NQKV  = 576;   // 3*C
constexpr int HID   = 384;   // 2*C

DEVI u16 f2bf(float f){
  union { float f; unsigned u; } v; v.f = f;
  return (u16)((v.u + 0x7fffu + ((v.u >> 16) & 1u)) >> 16);
}

// ---------------- prep: weight transposes (bf16) + packed bias table ----------------
__global__ void prep_kernel(const float* __restrict__ qkv_w,
                            const float* __restrict__ fc1_w,
                            const float* __restrict__ fc2_w,
                            const int*   __restrict__ rpi,
                            const float* __restrict__ rpb,
                            u16* __restrict__ qkvT,
                            u16* __restrict__ fc1T,
                            u16* __restrict__ fc2T,
                            float* __restrict__ bias_pk){
  int idx = blockIdx.x * blockDim.x + threadIdx.x;
  int stride = gridDim.x * blockDim.x;
  for(int i = idx; i < NQKV*C; i += stride){ int n = i / C,   k = i - n*C;   qkvT[i] = f2bf(qkv_w[k*NQKV + n]); }
  for(int i = idx; i < HID*C;  i += stride){ int n = i / C,   k = i - n*C;   fc1T[i] = f2bf(fc1_w[k*HID + n]); }
  for(int i = idx; i < C*HID;  i += stride){ int n = i / HID, k = i - n*HID; fc2T[i] = f2bf(fc2_w[k*C + n]); }
  const int n4 = HEADS*5*2*4*64*4;   // [head][chunk5][nf2][mi4][lane64][reg4]
  for(int i = idx; i < n4; i += stride){
    int t = i;
    int r    = t & 3;  t >>= 2;
    int lane = t & 63; t >>= 6;
    int mi   = t & 3;  t >>= 2;
    int nf   = t & 1;  t >>= 1;
    int chunk = t % 5; int head = t / 5;
    int g = lane >> 4, col = lane & 15;
    int q  = mi*16 + g*4 + r;
    int kk = chunk*32 + nf*16 + col;
    float v = 0.f;
    if(kk < 144) v = rpb[rpi[q*144 + kk]*HEADS + head];
    bias_pk[i] = v;
  }
}

// ---------------- LN1 + QKV GEMM: x[131072,192] -> qkv bf16 [131072,576] ----------------
__global__ void qkv_kernel(const float* __restrict__ x,
                           const float* __restrict__ g1,
                           const float* __restrict__ b1,
                           const u16* __restrict__ wT,     // [576][192] bf16
                           const float* __restrict__ qb,   // [576]
                           u16* __restrict__ qkv){
  __shared__ u16 xn[64][200];
  const int tid = threadIdx.x;
  const size_t tok0 = (size_t)blockIdx.x * 64;
  {
    const int trow = tid >> 3;
    const int j = tid & 7;
    const float* xr = x + (tok0 + trow)*C + j*24;
    float v[24];
    #pragma unroll
    for(int u_ = 0; u_ < 6; ++u_){
      float4 t = reinterpret_cast<const float4*>(xr)[u_];
      v[u_*4+0] = t.x; v[u_*4+1] = t.y; v[u_*4+2] = t.z; v[u_*4+3] = t.w;
    }
    float s1 = 0.f, s2 = 0.f;
    #pragma unroll
    for(int u_ = 0; u_ < 24; ++u_){ s1 += v[u_]; s2 += v[u_]*v[u_]; }
    #pragma unroll
    for(int m = 1; m < 8; m <<= 1){ s1 += __shfl_xor(s1, m, 64); s2 += __shfl_xor(s2, m, 64); }
    const float mean = s1 * (1.f/192.f);
    const float rstd = rsqrtf(s2*(1.f/192.f) - mean*mean + 1e-5f);
    #pragma unroll
    for(int u8 = 0; u8 < 3; ++u8){
      bf16x8 pk;
      #pragma unroll
      for(int e = 0; e < 8; ++e){
        int c = j*24 + u8*8 + e;
        pk[e] = (short)f2bf((v[u8*8+e] - mean)*rstd*g1[c] + b1[c]);
      }
      *reinterpret_cast<bf16x8*>(&xn[trow][j*24 + u8*8]) = pk;
    }
  }
  __syncthreads();
  const int lane = tid & 63;
  const int wave = tid >> 6;
  const int wm = wave >> 2;     // 0..1 : 32-row stripe
  const int wn = wave & 3;      // 0..3 : 144-col stripe
  const int g = lane >> 4, col = lane & 15;
  const f32x4 fzero = {0.f, 0.f, 0.f, 0.f};
  f32x4 acc[2][9];
  #pragma unroll
  for(int mi = 0; mi < 2; ++mi)
    #pragma unroll
    for(int nf = 0; nf < 9; ++nf) acc[mi][nf] = fzero;
  #pragma unroll
  for(int ks = 0; ks < 6; ++ks){
    bf16x8 a[2];
    #pragma unroll
    for(int mi = 0; mi < 2; ++mi)
      a[mi] = *reinterpret_cast<const bf16x8*>(&xn[wm*32 + mi*16 + col][ks*32 + g*8]);
    #pragma unroll
    for(int nf = 0; nf < 9; ++nf){
      const int n = wn*144 + nf*16 + col;
      bf16x8 bfr = *reinterpret_cast<const bf16x8*>(wT + (size_t)n*C + ks*32 + g*8);
      acc[0][nf] = __builtin_amdgcn_mfma_f32_16x16x32_bf16(a[0], bfr, acc[0][nf], 0, 0, 0);
      acc[1][nf] = __builtin_amdgcn_mfma_f32_16x16x32_bf16(a[1], bfr, acc[1][nf], 0, 0, 0);
    }
  }
  #pragma unroll
  for(int mi = 0; mi < 2; ++mi){
    #pragma unroll
    for(int nf = 0; nf < 9; ++nf){
      const int n = wn*144 + nf*16 + col;
      const float bb = qb[n];
      #pragma unroll
      for(int r = 0; r < 4; ++r){
        const int row = wm*32 + mi*16 + g*4 + r;
        qkv[(tok0 + row)*NQKV + n] = f2bf(acc[mi][nf][r] + bb);
      }
    }
  }
}

// ---------------- windowed attention (no softmax): per (window, head) ----------------
__global__ void attn_kernel(const u16* __restrict__ qkv,
                            const float* __restrict__ bias_pk,
                            const float* __restrict__ x,
                            float* __restrict__ out){
  __shared__ u16 Kl[160][40];   // K rows (12x12 window padded to 160) x d=32 (+pad)
  __shared__ u16 Vt[32][168];   // V^T: d x 160 (+pad)
  __shared__ u16 Pl[64][40];    // P chunk: 64 q-rows x 32 kv-cols (+pad)
  const int lane = threadIdx.x;
  const int g = lane >> 4, col = lane & 15;
  const int win = blockIdx.x, head = blockIdx.y;
  const int bt = win >> 8, wh = (win >> 4) & 15, ww = win & 15;
  const int h0 = wh*8, w0 = ww*8;
  const size_t base = (size_t)bt * 16384;
  const int coff = head*32 + g*8;
  // stage K and V^T (OOB / pad rows -> 0, matching reference zero-padding of k,v)
  #pragma unroll
  for(int i = 0; i < 10; ++i){
    const int kr = i*16 + col;
    const int r12 = (kr*2731) >> 15;       // kr/12
    const int c12 = kr - r12*12;
    const int hh = h0 - 2 + r12;
    const int wp = w0 - 2 + c12;
    bf16x8 kf = {0,0,0,0,0,0,0,0};
    bf16x8 vf = {0,0,0,0,0,0,0,0};
    if(kr < 144 && hh >= 0 && hh < 128 && wp >= 0 && wp < 128){
      const u16* p = qkv + (base + hh*128 + wp)*NQKV + coff;
      kf = *reinterpret_cast<const bf16x8*>(p + 192);
      vf = *reinterpret_cast<const bf16x8*>(p + 384);
    }
    *reinterpret_cast<bf16x8*>(&Kl[kr][g*8]) = kf;
    #pragma unroll
    for(int e = 0; e < 8; ++e) Vt[g*8 + e][kr] = (u16)vf[e];
  }
  // Q fragments (direct from global; rows = window-local q index)
  bf16x8 qf[4];
  #pragma unroll
  for(int mi = 0; mi < 4; ++mi){
    const int row = mi*16 + col;
    const int hh = h0 + (row >> 3), wp = w0 + (row & 7);
    qf[mi] = *reinterpret_cast<const bf16x8*>(qkv + (base + hh*128 + wp)*NQKV + coff);
  }
  const f32x4 fzero = {0.f, 0.f, 0.f, 0.f};
  f32x4 oacc[4][2];
  #pragma unroll
  for(int mi = 0; mi < 4; ++mi){ oacc[mi][0] = fzero; oacc[mi][1] = fzero; }
  const float scale = 0.17677669529663689f;  // 32^-0.5
  for(int ch = 0; ch < 5; ++ch){
    // S chunk = Q @ K^T  (M=64, N=32, K=32)
    f32x4 s[4][2];
    #pragma unroll
    for(int nf = 0; nf < 2; ++nf){
      bf16x8 kf = *reinterpret_cast<const bf16x8*>(&Kl[ch*32 + nf*16 + col][g*8]);
      #pragma unroll
      for(int mi = 0; mi < 4; ++mi)
        s[mi][nf] = __builtin_amdgcn_mfma_f32_16x16x32_bf16(qf[mi], kf, fzero, 0, 0, 0);
    }
    // scale + bias -> P (bf16 in LDS)
    #pragma unroll
    for(int nf = 0; nf < 2; ++nf){
      #pragma unroll
      for(int mi = 0; mi < 4; ++mi){
        const float4 bv = *reinterpret_cast<const float4*>(
            bias_pk + (size_t)((((head*5 + ch)*2 + nf)*4 + mi)*64 + lane)*4);
        const float* bvp = reinterpret_cast<const float*>(&bv);
        #pragma unroll
        for(int r = 0; r < 4; ++r)
          Pl[mi*16 + g*4 + r][nf*16 + col] = f2bf(s[mi][nf][r]*scale + bvp[r]);
      }
    }
    // O += P @ V  (M=64, N=32(d), K=32)
    bf16x8 pa[4];
    #pragma unroll
    for(int mi = 0; mi < 4; ++mi)
      pa[mi] = *reinterpret_cast<const bf16x8*>(&Pl[mi*16 + col][g*8]);
    #pragma unroll
    for(int nf = 0; nf < 2; ++nf){
      bf16x8 vfr = *reinterpret_cast<const bf16x8*>(&Vt[nf*16 + col][ch*32 + g*8]);
      #pragma unroll
      for(int mi = 0; mi < 4; ++mi)
        oacc[mi][nf] = __builtin_amdgcn_mfma_f32_16x16x32_bf16(pa[mi], vfr, oacc[mi][nf], 0, 0, 0);
    }
  }
  // epilogue: x1 = O + shortcut -> d_out (fp32)
  #pragma unroll
  for(int mi = 0; mi < 4; ++mi){
    #pragma unroll
    for(int nf = 0; nf < 2; ++nf){
      #pragma unroll
      for(int r = 0; r < 4; ++r){
        const int row = mi*16 + g*4 + r;
        const int hh = h0 + (row >> 3), wp = w0 + (row & 7);
        const size_t o = (base + hh*128 + wp)*(size_t)C + head*32 + nf*16 + col;
        out[o] = oacc[mi][nf][r] + x[o];
      }
    }
  }
}

// ---------------- LN2 + FC1 + GELU + FC2 + residual, in-place on d_out ----------------
__global__ void mlp_kernel(float* __restrict__ io,
                           const float* __restrict__ g2,
                           const float* __restrict__ b2,
                           const u16* __restrict__ w1T,    // [384][192]
                           const float* __restrict__ fb1,  // [384]
                           const u16* __restrict__ w2T,    // [192][384]
                           const float* __restrict__ fb2){ // [192]
  __shared__ u16 xn[64][200];
  __shared__ u16 hl[64][392];
  const int tid = threadIdx.x;
  const size_t tok0 = (size_t)blockIdx.x * 64;
  {
    const int trow = tid >> 3;
    const int j = tid & 7;
    const float* xr = io + (tok0 + trow)*C + j*24;
    float v[24];
    #pragma unroll
    for(int u_ = 0; u_ < 6; ++u_){
      float4 t = reinterpret_cast<const float4*>(xr)[u_];
      v[u_*4+0] = t.x; v[u_*4+1] = t.y; v[u_*4+2] = t.z; v[u_*4+3] = t.w;
    }
    float s1 = 0.f, s2 = 0.f;
    #pragma unroll
    for(int u_ = 0; u_ < 24; ++u_){ s1 += v[u_]; s2 += v[u_]*v[u_]; }
    #pragma unroll
    for(int m = 1; m < 8; m <<= 1){ s1 += __shfl_xor(s1, m, 64); s2 += __shfl_xor(s2, m, 64); }
    const float mean = s1 * (1.f/192.f);
    const float rstd = rsqrtf(s2*(1.f/192.f) - mean*mean + 1e-5f);
    #pragma unroll
    for(int u8 = 0; u8 < 3; ++u8){
      bf16x8 pk;
      #pragma unroll
      for(int e = 0; e < 8; ++e){
        int c = j*24 + u8*8 + e;
        pk[e] = (short)f2bf((v[u8*8+e] - mean)*rstd*g2[c] + b2[c]);
      }
      *reinterpret_cast<bf16x8*>(&xn[trow][j*24 + u8*8]) = pk;
    }
  }
  __syncthreads();
  const int lane = tid & 63, wave = tid >> 6;
  const int wm = wave >> 2, wn = wave & 3;
  const int g = lane >> 4, col = lane & 15;
  const f32x4 fzero = {0.f, 0.f, 0.f, 0.f};
  {
    f32x4 acc[2][6];
    #pragma unroll
    for(int mi = 0; mi < 2; ++mi)
      #pragma unroll
      for(int nf = 0; nf < 6; ++nf) acc[mi][nf] = fzero;
    #pragma unroll
    for(int ks = 0; ks < 6; ++ks){
      bf16x8 a[2];
      #pragma unroll
      for(int mi = 0; mi < 2; ++mi)
        a[mi] = *reinterpret_cast<const bf16x8*>(&xn[wm*32 + mi*16 + col][ks*32 + g*8]);
      #pragma unroll
      for(int nf = 0; nf < 6; ++nf){
        const int n = wn*96 + nf*16 + col;
        bf16x8 bfr = *reinterpret_cast<const bf16x8*>(w1T + (size_t)n*C + ks*32 + g*8);
        acc[0][nf] = __builtin_amdgcn_mfma_f32_16x16x32_bf16(a[0], bfr, acc[0][nf], 0, 0, 0);
        acc[1][nf] = __builtin_amdgcn_mfma_f32_16x16x32_bf16(a[1], bfr, acc[1][nf], 0, 0, 0);
      }
    }
    #pragma unroll
    for(int mi = 0; mi < 2; ++mi){
      #pragma unroll
      for(int nf = 0; nf < 6; ++nf){
        const int n = wn*96 + nf*16 + col;
        const float bb = fb1[n];
        #pragma unroll
        for(int r = 0; r < 4; ++r){
          const int row = wm*32 + mi*16 + g*4 + r;
          float hv = acc[mi][nf][r] + bb;
          hv = 0.5f * hv * (1.f + erff(hv * 0.70710678118654752f));  // exact gelu
          hl[row][n] = f2bf(hv);
        }
      }
    }
  }
  __syncthreads();
  {
    f32x4 acc[2][3];
    #pragma unroll
    for(int mi = 0; mi < 2; ++mi)
      #pragma unroll
      for(int nf = 0; nf < 3; ++nf) acc[mi][nf] = fzero;
    #pragma unroll
    for(int ks = 0; ks < 12; ++ks){
      bf16x8 a[2];
      #pragma unroll
      for(int mi = 0; mi < 2; ++mi)
        a[mi] = *reinterpret_cast<const bf16x8*>(&hl[wm*32 + mi*16 + col][ks*32 + g*8]);
      #pragma unroll
      for(int nf = 0; nf < 3; ++nf){
        const int n = wn*48 + nf*16 + col;
        bf16x8 bfr = *reinterpret_cast<const bf16x8*>(w2T + (size_t)n*HID + ks*32 + g*8);
        acc[0][nf] = __builtin_amdgcn_mfma_f32_16x16x32_bf16(a[0], bfr, acc[0][nf], 0, 0, 0);
        acc[1][nf] = __builtin_amdgcn_mfma_f32_16x16x32_bf16(a[1], bfr, acc[1][nf], 0, 0, 0);
      }
    }
    #pragma unroll
    for(int mi = 0; mi < 2; ++mi){
      #pragma unroll
      for(int nf = 0; nf < 3; ++nf){
        const int n = wn*48 + nf*16 + col;
        const float bb = fb2[n];
        #pragma unroll
        for(int r = 0; r < 4; ++r){
          const int row = wm*32 + mi*16 + g*4 + r;
          const size_t idx = (tok0 + row)*C + n;
          io[idx] = acc[mi][nf][r] + bb + io[idx];   // + residual x1 (each element owned by this thread)
        }
      }
    }
  }
}

extern "C" void kernel_launch(void* const* d_in, const int* in_sizes, int n_in,
                              void* d_out, int out_size, void* d_ws, size_t ws_size,
                              hipStream_t stream){
  const float* x    = (const float*)d_in[0];
  const int*   rpi  = (const int*)  d_in[2];
  const float* n1g  = (const float*)d_in[3];
  const float* n1b  = (const float*)d_in[4];
  const float* qkvw = (const float*)d_in[5];
  const float* qkvb = (const float*)d_in[6];
  const float* rpb  = (const float*)d_in[7];
  const float* n2g  = (const float*)d_in[8];
  const float* n2b  = (const float*)d_in[9];
  const float* fc1w = (const float*)d_in[10];
  const float* fc1b = (const float*)d_in[11];
  const float* fc2w = (const float*)d_in[12];
  const float* fc2b = (const float*)d_in[13];
  float* out = (float*)d_out;
  char* ws = (char*)d_ws;
  u16*   qkvT    = (u16*)  (ws + 0);          // 576*192*2   = 221184
  u16*   fc1T    = (u16*)  (ws + 221184);     // 384*192*2   = 147456
  u16*   fc2T    = (u16*)  (ws + 368640);     // 192*384*2   = 147456
  float* bias_pk = (float*)(ws + 516096);     // 245760*4    = 983040
  u16*   qkvbuf  = (u16*)  (ws + 1499136);    // 131072*576*2 = 150994944
  if(ws_size < 152494080ull) return;          // insufficient scratch -> visible failure
  prep_kernel<<<dim3(512), dim3(256), 0, stream>>>(qkvw, fc1w, fc2w, rpi, rpb, qkvT, fc1T, fc2T, bias_pk);
  qkv_kernel<<<dim3(2048), dim3(512), 0, stream>>>(x, n1g, n1b, qkvT, qkvb, qkvbuf);
  attn_kernel<<<dim3(2048, 6), dim3(64), 0, stream>>>(qkvbuf, bias_pk, x, out);
  mlp_kernel<<<dim3(2048), dim3(512), 0, stream>>>(out, n2g, n2b, fc1T, fc1b, fc2T, fc2b);
}

// Round 2
// 446.736 us; speedup vs baseline: 1.0665x; 1.0665x over previous
//
#include <hip/hip_runtime.h>
#include <cstdint>
#include <cstddef>

typedef short bf16x8 __attribute__((ext_vector_type(8)));
typedef float f32x4  __attribute__((ext_vector_type(4)));
typedef unsigned short u16;

#define DEVI __device__ __forceinline__

constexpr int C     = 192;
constexpr int HEADS = 6;
constexpr int NQKV  = 576;   // 3*C
constexpr int HID   = 384;   // 2*C

DEVI u16 f2bf(float f){
  union { float f; unsigned u; } v; v.f = f;
  return (u16)((v.u + 0x7fffu + ((v.u >> 16) & 1u)) >> 16);
}

// ---------------- prep: weight transposes (bf16) + packed bias table ----------------
__global__ void prep_kernel(const float* __restrict__ qkv_w,
                            const float* __restrict__ fc1_w,
                            const float* __restrict__ fc2_w,
                            const int*   __restrict__ rpi,
                            const float* __restrict__ rpb,
                            u16* __restrict__ qkvT,
                            u16* __restrict__ fc1T,
                            u16* __restrict__ fc2T,
                            float* __restrict__ bias_pk){
  int idx = blockIdx.x * blockDim.x + threadIdx.x;
  int stride = gridDim.x * blockDim.x;
  for(int i = idx; i < NQKV*C; i += stride){ int n = i / C,   k = i - n*C;   qkvT[i] = f2bf(qkv_w[k*NQKV + n]); }
  for(int i = idx; i < HID*C;  i += stride){ int n = i / C,   k = i - n*C;   fc1T[i] = f2bf(fc1_w[k*HID + n]); }
  for(int i = idx; i < C*HID;  i += stride){ int n = i / HID, k = i - n*HID; fc2T[i] = f2bf(fc2_w[k*C + n]); }
  const int n4 = HEADS*5*2*4*64*4;   // [head][chunk5][nf2][mi4][lane64][reg4]
  for(int i = idx; i < n4; i += stride){
    int t = i;
    int r    = t & 3;  t >>= 2;
    int lane = t & 63; t >>= 6;
    int mi   = t & 3;  t >>= 2;
    int nf   = t & 1;  t >>= 1;
    int chunk = t % 5; int head = t / 5;
    int g = lane >> 4, col = lane & 15;
    int q  = mi*16 + g*4 + r;
    int kk = chunk*32 + nf*16 + col;
    float v = 0.f;
    if(kk < 144) v = rpb[rpi[q*144 + kk]*HEADS + head];
    bias_pk[i] = v;
  }
}

// ---------------- LN1 + QKV GEMM: x[131072,192] -> qkv bf16 [131072,576] ----------------
// 64 tokens/block, 6 waves; each wave: all 64 rows x 96-col stripe -> acc[4][6] (4 MFMA / weight load)
__global__ __launch_bounds__(384, 3)
void qkv_kernel(const float* __restrict__ x,
                const float* __restrict__ g1,
                const float* __restrict__ b1,
                const u16* __restrict__ wT,     // [576][192] bf16
                const float* __restrict__ qb,   // [576]
                u16* __restrict__ qkv){
  __shared__ u16 xn[64][200];
  const int tid = threadIdx.x;
  const size_t tok0 = (size_t)blockIdx.x * 64;
  if(tid < 256){
    const int trow = tid >> 2;       // 0..63
    const int j = tid & 3;           // 0..3, 48 floats each
    const float* xr = x + (tok0 + trow)*C + j*48;
    float v[48];
    #pragma unroll
    for(int u_ = 0; u_ < 12; ++u_){
      float4 t = reinterpret_cast<const float4*>(xr)[u_];
      v[u_*4+0] = t.x; v[u_*4+1] = t.y; v[u_*4+2] = t.z; v[u_*4+3] = t.w;
    }
    float s1 = 0.f, s2 = 0.f;
    #pragma unroll
    for(int u_ = 0; u_ < 48; ++u_){ s1 += v[u_]; s2 += v[u_]*v[u_]; }
    s1 += __shfl_xor(s1, 1, 64); s2 += __shfl_xor(s2, 1, 64);
    s1 += __shfl_xor(s1, 2, 64); s2 += __shfl_xor(s2, 2, 64);
    const float mean = s1 * (1.f/192.f);
    const float rstd = rsqrtf(s2*(1.f/192.f) - mean*mean + 1e-5f);
    #pragma unroll
    for(int u8 = 0; u8 < 6; ++u8){
      bf16x8 pk;
      #pragma unroll
      for(int e = 0; e < 8; ++e){
        int c = j*48 + u8*8 + e;
        pk[e] = (short)f2bf((v[u8*8+e] - mean)*rstd*g1[c] + b1[c]);
      }
      *reinterpret_cast<bf16x8*>(&xn[trow][j*48 + u8*8]) = pk;
    }
  }
  __syncthreads();
  const int lane = tid & 63;
  const int wn = tid >> 6;      // 0..5 : 96-col stripe
  const int g = lane >> 4, col = lane & 15;
  const f32x4 fzero = {0.f, 0.f, 0.f, 0.f};
  f32x4 acc[4][6];
  #pragma unroll
  for(int mi = 0; mi < 4; ++mi)
    #pragma unroll
    for(int nf = 0; nf < 6; ++nf) acc[mi][nf] = fzero;
  const u16* wbase = wT + (size_t)(wn*96 + col)*C + g*8;
  #pragma unroll
  for(int ks = 0; ks < 6; ++ks){
    bf16x8 wf[6];
    #pragma unroll
    for(int nf = 0; nf < 6; ++nf)
      wf[nf] = *reinterpret_cast<const bf16x8*>(wbase + (size_t)nf*16*C + ks*32);
    bf16x8 a[4];
    #pragma unroll
    for(int mi = 0; mi < 4; ++mi)
      a[mi] = *reinterpret_cast<const bf16x8*>(&xn[mi*16 + col][ks*32 + g*8]);
    #pragma unroll
    for(int nf = 0; nf < 6; ++nf)
      #pragma unroll
      for(int mi = 0; mi < 4; ++mi)
        acc[mi][nf] = __builtin_amdgcn_mfma_f32_16x16x32_bf16(a[mi], wf[nf], acc[mi][nf], 0, 0, 0);
  }
  #pragma unroll
  for(int mi = 0; mi < 4; ++mi){
    #pragma unroll
    for(int nf = 0; nf < 6; ++nf){
      const int n = wn*96 + nf*16 + col;
      const float bb = qb[n];
      #pragma unroll
      for(int r = 0; r < 4; ++r){
        const int row = mi*16 + g*4 + r;
        qkv[(tok0 + row)*NQKV + n] = f2bf(acc[mi][nf][r] + bb);
      }
    }
  }
}

// ---------------- windowed attention (no softmax): per (window, head) ----------------
__global__ void attn_kernel(const u16* __restrict__ qkv,
                            const float* __restrict__ bias_pk,
                            const float* __restrict__ x,
                            float* __restrict__ out){
  __shared__ u16 Kl[160][40];   // K rows (12x12 window padded to 160) x d=32 (+pad)
  __shared__ u16 Vt[32][168];   // V^T: d x 160 (+pad)
  __shared__ u16 Pl[64][40];    // P chunk: 64 q-rows x 32 kv-cols (+pad)
  const int lane = threadIdx.x;
  const int g = lane >> 4, col = lane & 15;
  const int win = blockIdx.x, head = blockIdx.y;
  const int bt = win >> 8, wh = (win >> 4) & 15, ww = win & 15;
  const int h0 = wh*8, w0 = ww*8;
  const size_t base = (size_t)bt * 16384;
  const int coff = head*32 + g*8;
  // stage K and V^T (OOB / pad rows -> 0, matching reference zero-padding of k,v)
  #pragma unroll
  for(int i = 0; i < 10; ++i){
    const int kr = i*16 + col;
    const int r12 = (kr*2731) >> 15;       // kr/12
    const int c12 = kr - r12*12;
    const int hh = h0 - 2 + r12;
    const int wp = w0 - 2 + c12;
    bf16x8 kf = {0,0,0,0,0,0,0,0};
    bf16x8 vf = {0,0,0,0,0,0,0,0};
    if(kr < 144 && hh >= 0 && hh < 128 && wp >= 0 && wp < 128){
      const u16* p = qkv + (base + hh*128 + wp)*NQKV + coff;
      kf = *reinterpret_cast<const bf16x8*>(p + 192);
      vf = *reinterpret_cast<const bf16x8*>(p + 384);
    }
    *reinterpret_cast<bf16x8*>(&Kl[kr][g*8]) = kf;
    #pragma unroll
    for(int e = 0; e < 8; ++e) Vt[g*8 + e][kr] = (u16)vf[e];
  }
  // Q fragments (direct from global; rows = window-local q index)
  bf16x8 qf[4];
  #pragma unroll
  for(int mi = 0; mi < 4; ++mi){
    const int row = mi*16 + col;
    const int hh = h0 + (row >> 3), wp = w0 + (row & 7);
    qf[mi] = *reinterpret_cast<const bf16x8*>(qkv + (base + hh*128 + wp)*NQKV + coff);
  }
  const f32x4 fzero = {0.f, 0.f, 0.f, 0.f};
  f32x4 oacc[4][2];
  #pragma unroll
  for(int mi = 0; mi < 4; ++mi){ oacc[mi][0] = fzero; oacc[mi][1] = fzero; }
  const float scale = 0.17677669529663689f;  // 32^-0.5
  for(int ch = 0; ch < 5; ++ch){
    // S chunk = Q @ K^T  (M=64, N=32, K=32)
    f32x4 s[4][2];
    #pragma unroll
    for(int nf = 0; nf < 2; ++nf){
      bf16x8 kf = *reinterpret_cast<const bf16x8*>(&Kl[ch*32 + nf*16 + col][g*8]);
      #pragma unroll
      for(int mi = 0; mi < 4; ++mi)
        s[mi][nf] = __builtin_amdgcn_mfma_f32_16x16x32_bf16(qf[mi], kf, fzero, 0, 0, 0);
    }
    // scale + bias -> P (bf16 in LDS)
    #pragma unroll
    for(int nf = 0; nf < 2; ++nf){
      #pragma unroll
      for(int mi = 0; mi < 4; ++mi){
        const float4 bv = *reinterpret_cast<const float4*>(
            bias_pk + (size_t)((((head*5 + ch)*2 + nf)*4 + mi)*64 + lane)*4);
        const float* bvp = reinterpret_cast<const float*>(&bv);
        #pragma unroll
        for(int r = 0; r < 4; ++r)
          Pl[mi*16 + g*4 + r][nf*16 + col] = f2bf(s[mi][nf][r]*scale + bvp[r]);
      }
    }
    // O += P @ V  (M=64, N=32(d), K=32)
    bf16x8 pa[4];
    #pragma unroll
    for(int mi = 0; mi < 4; ++mi)
      pa[mi] = *reinterpret_cast<const bf16x8*>(&Pl[mi*16 + col][g*8]);
    #pragma unroll
    for(int nf = 0; nf < 2; ++nf){
      bf16x8 vfr = *reinterpret_cast<const bf16x8*>(&Vt[nf*16 + col][ch*32 + g*8]);
      #pragma unroll
      for(int mi = 0; mi < 4; ++mi)
        oacc[mi][nf] = __builtin_amdgcn_mfma_f32_16x16x32_bf16(pa[mi], vfr, oacc[mi][nf], 0, 0, 0);
    }
  }
  // epilogue: x1 = O + shortcut -> d_out (fp32)
  #pragma unroll
  for(int mi = 0; mi < 4; ++mi){
    #pragma unroll
    for(int nf = 0; nf < 2; ++nf){
      #pragma unroll
      for(int r = 0; r < 4; ++r){
        const int row = mi*16 + g*4 + r;
        const int hh = h0 + (row >> 3), wp = w0 + (row & 7);
        const size_t o = (base + hh*128 + wp)*(size_t)C + head*32 + nf*16 + col;
        out[o] = oacc[mi][nf][r] + x[o];
      }
    }
  }
}

// ---------------- LN2 + FC1 + GELU + FC2 + residual, in-place on d_out ----------------
// 128 tokens/block, 8 waves (wm2 x wn4); hid processed in 2 halves to keep LDS at 102KB.
// Each wave: 64 rows x 48 cols -> acc[4][3], 4 MFMA per weight load.
__global__ __launch_bounds__(512, 2)
void mlp_kernel(float* __restrict__ io,
                const float* __restrict__ g2,
                const float* __restrict__ b2,
                const u16* __restrict__ w1T,    // [384][192]
                const float* __restrict__ fb1,  // [384]
                const u16* __restrict__ w2T,    // [192][384]
                const float* __restrict__ fb2){ // [192]
  __shared__ u16 xn[128][200];
  __shared__ u16 hl[128][200];
  const int tid = threadIdx.x;
  const size_t tok0 = (size_t)blockIdx.x * 128;
  {
    const int trow = tid >> 2;    // 0..127
    const int j = tid & 3;        // 48 floats each
    const float* xr = io + (tok0 + trow)*C + j*48;
    float v[48];
    #pragma unroll
    for(int u_ = 0; u_ < 12; ++u_){
      float4 t = reinterpret_cast<const float4*>(xr)[u_];
      v[u_*4+0] = t.x; v[u_*4+1] = t.y; v[u_*4+2] = t.z; v[u_*4+3] = t.w;
    }
    float s1 = 0.f, s2 = 0.f;
    #pragma unroll
    for(int u_ = 0; u_ < 48; ++u_){ s1 += v[u_]; s2 += v[u_]*v[u_]; }
    s1 += __shfl_xor(s1, 1, 64); s2 += __shfl_xor(s2, 1, 64);
    s1 += __shfl_xor(s1, 2, 64); s2 += __shfl_xor(s2, 2, 64);
    const float mean = s1 * (1.f/192.f);
    const float rstd = rsqrtf(s2*(1.f/192.f) - mean*mean + 1e-5f);
    #pragma unroll
    for(int u8 = 0; u8 < 6; ++u8){
      bf16x8 pk;
      #pragma unroll
      for(int e = 0; e < 8; ++e){
        int c = j*48 + u8*8 + e;
        pk[e] = (short)f2bf((v[u8*8+e] - mean)*rstd*g2[c] + b2[c]);
      }
      *reinterpret_cast<bf16x8*>(&xn[trow][j*48 + u8*8]) = pk;
    }
  }
  __syncthreads();
  const int lane = tid & 63, wave = tid >> 6;
  const int wm = wave >> 2;       // 0..1 : 64-row stripe
  const int wn = wave & 3;        // 0..3 : 48-col stripe
  const int g = lane >> 4, col = lane & 15;
  const f32x4 fzero = {0.f, 0.f, 0.f, 0.f};
  f32x4 acc2[4][3];
  #pragma unroll
  for(int mi = 0; mi < 4; ++mi)
    #pragma unroll
    for(int nf = 0; nf < 3; ++nf) acc2[mi][nf] = fzero;
  #pragma unroll
  for(int hb = 0; hb < 2; ++hb){
    // FC1 half: hid cols [hb*192 + wn*48, +48)
    f32x4 acc1[4][3];
    #pragma unroll
    for(int mi = 0; mi < 4; ++mi)
      #pragma unroll
      for(int nf = 0; nf < 3; ++nf) acc1[mi][nf] = fzero;
    const u16* w1base = w1T + (size_t)(hb*192 + wn*48 + col)*C + g*8;
    #pragma unroll
    for(int ks = 0; ks < 6; ++ks){
      bf16x8 wf[3];
      #pragma unroll
      for(int nf = 0; nf < 3; ++nf)
        wf[nf] = *reinterpret_cast<const bf16x8*>(w1base + (size_t)nf*16*C + ks*32);
      bf16x8 a[4];
      #pragma unroll
      for(int mi = 0; mi < 4; ++mi)
        a[mi] = *reinterpret_cast<const bf16x8*>(&xn[wm*64 + mi*16 + col][ks*32 + g*8]);
      #pragma unroll
      for(int nf = 0; nf < 3; ++nf)
        #pragma unroll
        for(int mi = 0; mi < 4; ++mi)
          acc1[mi][nf] = __builtin_amdgcn_mfma_f32_16x16x32_bf16(a[mi], wf[nf], acc1[mi][nf], 0, 0, 0);
    }
    // bias + exact gelu -> hl (local cols 0..191)
    #pragma unroll
    for(int mi = 0; mi < 4; ++mi){
      #pragma unroll
      for(int nf = 0; nf < 3; ++nf){
        const int nl = wn*48 + nf*16 + col;
        const float bb = fb1[hb*192 + nl];
        #pragma unroll
        for(int r = 0; r < 4; ++r){
          const int row = wm*64 + mi*16 + g*4 + r;
          float hv = acc1[mi][nf][r] + bb;
          hv = 0.5f * hv * (1.f + erff(hv * 0.70710678118654752f));
          hl[row][nl] = f2bf(hv);
        }
      }
    }
    __syncthreads();   // hl half ready
    // FC2 partial k-sweep over this half
    const u16* w2base = w2T + (size_t)(wn*48 + col)*HID + hb*192 + g*8;
    #pragma unroll
    for(int ks = 0; ks < 6; ++ks){
      bf16x8 wf[3];
      #pragma unroll
      for(int nf = 0; nf < 3; ++nf)
        wf[nf] = *reinterpret_cast<const bf16x8*>(w2base + (size_t)nf*16*HID + ks*32);
      bf16x8 a[4];
      #pragma unroll
      for(int mi = 0; mi < 4; ++mi)
        a[mi] = *reinterpret_cast<const bf16x8*>(&hl[wm*64 + mi*16 + col][ks*32 + g*8]);
      #pragma unroll
      for(int nf = 0; nf < 3; ++nf)
        #pragma unroll
        for(int mi = 0; mi < 4; ++mi)
          acc2[mi][nf] = __builtin_amdgcn_mfma_f32_16x16x32_bf16(a[mi], wf[nf], acc2[mi][nf], 0, 0, 0);
    }
    __syncthreads();   // hl consumed; safe to overwrite next half
  }
  #pragma unroll
  for(int mi = 0; mi < 4; ++mi){
    #pragma unroll
    for(int nf = 0; nf < 3; ++nf){
      const int n = wn*48 + nf*16 + col;
      const float bb = fb2[n];
      #pragma unroll
      for(int r = 0; r < 4; ++r){
        const int row = wm*64 + mi*16 + g*4 + r;
        const size_t idx = (tok0 + row)*C + n;
        io[idx] = acc2[mi][nf][r] + bb + io[idx];   // + residual x1
      }
    }
  }
}

extern "C" void kernel_launch(void* const* d_in, const int* in_sizes, int n_in,
                              void* d_out, int out_size, void* d_ws, size_t ws_size,
                              hipStream_t stream){
  const float* x    = (const float*)d_in[0];
  const int*   rpi  = (const int*)  d_in[2];
  const float* n1g  = (const float*)d_in[3];
  const float* n1b  = (const float*)d_in[4];
  const float* qkvw = (const float*)d_in[5];
  const float* qkvb = (const float*)d_in[6];
  const float* rpb  = (const float*)d_in[7];
  const float* n2g  = (const float*)d_in[8];
  const float* n2b  = (const float*)d_in[9];
  const float* fc1w = (const float*)d_in[10];
  const float* fc1b = (const float*)d_in[11];
  const float* fc2w = (const float*)d_in[12];
  const float* fc2b = (const float*)d_in[13];
  float* out = (float*)d_out;
  char* ws = (char*)d_ws;
  u16*   qkvT    = (u16*)  (ws + 0);          // 576*192*2   = 221184
  u16*   fc1T    = (u16*)  (ws + 221184);     // 384*192*2   = 147456
  u16*   fc2T    = (u16*)  (ws + 368640);     // 192*384*2   = 147456
  float* bias_pk = (float*)(ws + 516096);     // 245760*4    = 983040
  u16*   qkvbuf  = (u16*)  (ws + 1499136);    // 131072*576*2 = 150994944
  if(ws_size < 152494080ull) return;          // insufficient scratch -> visible failure
  prep_kernel<<<dim3(512), dim3(256), 0, stream>>>(qkvw, fc1w, fc2w, rpi, rpb, qkvT, fc1T, fc2T, bias_pk);
  qkv_kernel<<<dim3(2048), dim3(384), 0, stream>>>(x, n1g, n1b, qkvT, qkvb, qkvbuf);
  attn_kernel<<<dim3(2048, 6), dim3(64), 0, stream>>>(qkvbuf, bias_pk, x, out);
  mlp_kernel<<<dim3(1024), dim3(512), 0, stream>>>(out, n2g, n2b, fc1T, fc1b, fc2T, fc2b);
}

// Round 3
// 301.985 us; speedup vs baseline: 1.5776x; 1.4793x over previous
//
#include <hip/hip_runtime.h>
#include <cstdint>
#include <cstddef>

typedef short bf16x8 __attribute__((ext_vector_type(8)));
typedef unsigned short u16x4 __attribute__((ext_vector_type(4)));
typedef float f32x4  __attribute__((ext_vector_type(4)));
typedef unsigned short u16;

#define DEVI __device__ __forceinline__

constexpr int C     = 192;
constexpr int HEADS = 6;
constexpr int NQKV  = 576;   // 3*C
constexpr int HID   = 384;   // 2*C
constexpr int NTOK  = 131072;

DEVI u16 f2bf(float f){
  union { float f; unsigned u; } v; v.f = f;
  return (u16)((v.u + 0x7fffu + ((v.u >> 16) & 1u)) >> 16);
}

// exact-enough GELU: A&S 7.1.26 erf (max abs err 1.5e-7), branchless
DEVI float gelu(float xx){
  float y  = xx * 0.70710678118654752f;
  float ay = fabsf(y);
  float t  = __builtin_amdgcn_rcpf(1.0f + 0.3275911f * ay);
  float p  = t*(0.254829592f + t*(-0.284496736f + t*(1.421413741f + t*(-1.453152027f + t*1.061405429f))));
  float e  = __expf(-(y*y));
  float er = copysignf(1.0f - p*e, y);
  return 0.5f * xx * (1.0f + er);
}

// ---------------- prep: fragment-packed weights + packed bias table ----------------
// packed layout: [(panel*KS + ks)][lane][8e] ; value = W[k = ks*32 + (lane>>4)*8 + e][n = panel*16 + (lane&15)]
__global__ void prep_kernel(const float* __restrict__ qkv_w,
                            const float* __restrict__ fc1_w,
                            const float* __restrict__ fc2_w,
                            const int*   __restrict__ rpi,
                            const float* __restrict__ rpb,
                            u16* __restrict__ qkvP,
                            u16* __restrict__ fc1P,
                            u16* __restrict__ fc2P,
                            float* __restrict__ bias_pk){
  int idx = blockIdx.x * blockDim.x + threadIdx.x;
  int stride = gridDim.x * blockDim.x;
  // qkvP: 36 panels x 6 ks
  for(int i = idx; i < 36*6*64*8; i += stride){
    int e = i & 7, lane = (i >> 3) & 63, t = i >> 9;
    int ks = t % 6, p = t / 6;
    int n = p*16 + (lane & 15), k = ks*32 + (lane >> 4)*8 + e;
    qkvP[i] = f2bf(qkv_w[k*NQKV + n]);
  }
  // fc1P: 24 panels x 6 ks
  for(int i = idx; i < 24*6*64*8; i += stride){
    int e = i & 7, lane = (i >> 3) & 63, t = i >> 9;
    int ks = t % 6, p = t / 6;
    int n = p*16 + (lane & 15), k = ks*32 + (lane >> 4)*8 + e;
    fc1P[i] = f2bf(fc1_w[k*HID + n]);
  }
  // fc2P: 12 panels x 12 ks
  for(int i = idx; i < 12*12*64*8; i += stride){
    int e = i & 7, lane = (i >> 3) & 63, t = i >> 9;
    int ks = t % 12, p = t / 12;
    int n = p*16 + (lane & 15), k = ks*32 + (lane >> 4)*8 + e;
    fc2P[i] = f2bf(fc2_w[k*C + n]);
  }
  // bias_pk: [head][chunk5][nf2][mi4][lane64][reg4]
  const int n4 = HEADS*5*2*4*64*4;
  for(int i = idx; i < n4; i += stride){
    int t = i;
    int r    = t & 3;  t >>= 2;
    int lane = t & 63; t >>= 6;
    int mi   = t & 3;  t >>= 2;
    int nf   = t & 1;  t >>= 1;
    int chunk = t % 5; int head = t / 5;
    int g = lane >> 4, col = lane & 15;
    int q  = mi*16 + g*4 + r;
    int kk = chunk*32 + nf*16 + col;
    float v = 0.f;
    if(kk < 144) v = rpb[rpi[q*144 + kk]*HEADS + head];
    bias_pk[i] = v;
  }
}

// ---------------- LN1 + QKV GEMM -> head-planar qkv bf16 [18 planes][131072][32] ----------------
__global__ __launch_bounds__(384, 3)
void qkv_kernel(const float* __restrict__ x,
                const float* __restrict__ g1,
                const float* __restrict__ b1,
                const u16* __restrict__ wP,     // fragment-packed qkv weights
                const float* __restrict__ qb,   // [576]
                u16* __restrict__ qkv){         // head-planar
  __shared__ u16 xn[64][200];
  __shared__ u16 rp[64][296];
  const int tid = threadIdx.x;
  const size_t tok0 = (size_t)blockIdx.x * 64;
  if(tid < 256){
    const int trow = tid >> 2;   // 0..63
    const int j = tid & 3;       // 0..3
    const float* xr = x + (tok0 + trow)*C;
    float4 xv[12];
    #pragma unroll
    for(int u = 0; u < 12; ++u)
      xv[u] = *reinterpret_cast<const float4*>(xr + u*16 + j*4);   // 64B per 4-lane quad
    float s1 = 0.f, s2 = 0.f;
    #pragma unroll
    for(int u = 0; u < 12; ++u){
      const float* f = reinterpret_cast<const float*>(&xv[u]);
      #pragma unroll
      for(int e = 0; e < 4; ++e){ s1 += f[e]; s2 += f[e]*f[e]; }
    }
    s1 += __shfl_xor(s1, 1, 64); s2 += __shfl_xor(s2, 1, 64);
    s1 += __shfl_xor(s1, 2, 64); s2 += __shfl_xor(s2, 2, 64);
    const float mean = s1 * (1.f/192.f);
    const float rstd = rsqrtf(s2*(1.f/192.f) - mean*mean + 1e-5f);
    #pragma unroll
    for(int u = 0; u < 12; ++u){
      const float4 gv = *reinterpret_cast<const float4*>(g1 + u*16 + j*4);
      const float4 bv = *reinterpret_cast<const float4*>(b1 + u*16 + j*4);
      const float* f = reinterpret_cast<const float*>(&xv[u]);
      const float* gp = reinterpret_cast<const float*>(&gv);
      const float* bp = reinterpret_cast<const float*>(&bv);
      u16x4 pk;
      #pragma unroll
      for(int e = 0; e < 4; ++e) pk[e] = f2bf((f[e] - mean)*rstd*gp[e] + bp[e]);
      *reinterpret_cast<u16x4*>(&xn[trow][u*16 + j*4]) = pk;
    }
  }
  __syncthreads();
  const int lane = tid & 63;
  const int wn = tid >> 6;      // 0..5 : 96-col stripe
  const int g = lane >> 4, col = lane & 15;
  const f32x4 fzero = {0.f, 0.f, 0.f, 0.f};
  f32x4 acc[4][6];
  #pragma unroll
  for(int mi = 0; mi < 4; ++mi)
    #pragma unroll
    for(int nf = 0; nf < 6; ++nf) acc[mi][nf] = fzero;
  #pragma unroll
  for(int ks = 0; ks < 6; ++ks){
    bf16x8 wf[6];
    #pragma unroll
    for(int nf = 0; nf < 6; ++nf)
      wf[nf] = *reinterpret_cast<const bf16x8*>(wP + ((size_t)(((wn*6 + nf)*6 + ks)*64) + lane)*8);
    bf16x8 a[4];
    #pragma unroll
    for(int mi = 0; mi < 4; ++mi)
      a[mi] = *reinterpret_cast<const bf16x8*>(&xn[mi*16 + col][ks*32 + g*8]);
    #pragma unroll
    for(int nf = 0; nf < 6; ++nf)
      #pragma unroll
      for(int mi = 0; mi < 4; ++mi)
        acc[mi][nf] = __builtin_amdgcn_mfma_f32_16x16x32_bf16(a[mi], wf[nf], acc[mi][nf], 0, 0, 0);
  }
  // epilogue: repack halves (288 cols = 9 planes) in LDS, then coalesced plane stores
  #pragma unroll
  for(int h = 0; h < 2; ++h){
    if(wn >= h*3 && wn < h*3 + 3){
      const int wl = wn - h*3;
      #pragma unroll
      for(int mi = 0; mi < 4; ++mi){
        #pragma unroll
        for(int nf = 0; nf < 6; ++nf){
          const int nloc = wl*96 + nf*16 + col;
          const float bb = qb[h*288 + nloc];
          #pragma unroll
          for(int r = 0; r < 4; ++r)
            rp[mi*16 + g*4 + r][nloc] = f2bf(acc[mi][nf][r] + bb);
        }
      }
    }
    __syncthreads();     // rp half ready
    for(int c = tid; c < 2304; c += 384){
      const int pl = c >> 8, rr = c & 255, tok = rr >> 2, dc = rr & 3;
      bf16x8 vv = *reinterpret_cast<const bf16x8*>(&rp[tok][pl*32 + dc*8]);
      *reinterpret_cast<bf16x8*>(qkv + ((size_t)(h*9 + pl)*NTOK + tok0 + tok)*32 + dc*8) = vv;
    }
    __syncthreads();     // rp consumed
  }
}

// ---------------- windowed attention (no softmax): per (window, head), head-planar input ----------------
__global__ __launch_bounds__(64, 2)
void attn_kernel(const u16* __restrict__ qkv,   // [18][131072][32]
                 const float* __restrict__ bias_pk,
                 const float* __restrict__ x,
                 float* __restrict__ out){
  __shared__ u16 Vt[32][168];   // V^T: d x 160 (+pad)
  __shared__ u16 Pl[64][40];    // P chunk: 64 q-rows x 32 kv-cols (+pad)
  const int lane = threadIdx.x;
  const int g = lane >> 4, col = lane & 15;
  const int win = blockIdx.x, head = blockIdx.y;
  const int bt = win >> 8, wh = (win >> 4) & 15, ww = win & 15;
  const int h0 = wh*8, w0 = ww*8;
  const size_t tokbase = (size_t)bt * 16384;
  const u16* Qp = qkv + (size_t)head      *NTOK*32;
  const u16* Kp = qkv + (size_t)(6 + head)*NTOK*32;
  const u16* Vp = qkv + (size_t)(12 + head)*NTOK*32;
  // K fragments direct to registers (staging pattern == fragment pattern); V -> LDS transpose
  bf16x8 kf[10];
  #pragma unroll
  for(int i = 0; i < 10; ++i){
    const int kr = i*16 + col;
    const int r12 = (kr*2731) >> 15;       // kr/12
    const int c12 = kr - r12*12;
    const int hh = h0 - 2 + r12;
    const int wp = w0 - 2 + c12;
    bf16x8 kv_ = {0,0,0,0,0,0,0,0};
    bf16x8 vv_ = {0,0,0,0,0,0,0,0};
    if(kr < 144 && hh >= 0 && hh < 128 && wp >= 0 && wp < 128){
      const size_t t = tokbase + hh*128 + wp;
      kv_ = *reinterpret_cast<const bf16x8*>(Kp + t*32 + g*8);
      vv_ = *reinterpret_cast<const bf16x8*>(Vp + t*32 + g*8);
    }
    kf[i] = kv_;
    #pragma unroll
    for(int e = 0; e < 8; ++e) Vt[g*8 + e][kr] = (u16)vv_[e];
  }
  bf16x8 qf[4];
  #pragma unroll
  for(int mi = 0; mi < 4; ++mi){
    const int row = mi*16 + col;
    const size_t t = tokbase + (size_t)(h0 + (row >> 3))*128 + w0 + (row & 7);
    qf[mi] = *reinterpret_cast<const bf16x8*>(Qp + t*32 + g*8);
  }
  const f32x4 fzero = {0.f, 0.f, 0.f, 0.f};
  f32x4 oacc[4][2];
  #pragma unroll
  for(int mi = 0; mi < 4; ++mi){ oacc[mi][0] = fzero; oacc[mi][1] = fzero; }
  const float scale = 0.17677669529663689f;  // 32^-0.5
  for(int ch = 0; ch < 5; ++ch){
    f32x4 s[4][2];
    #pragma unroll
    for(int nf = 0; nf < 2; ++nf){
      const bf16x8 kk = kf[ch*2 + nf];
      #pragma unroll
      for(int mi = 0; mi < 4; ++mi)
        s[mi][nf] = __builtin_amdgcn_mfma_f32_16x16x32_bf16(qf[mi], kk, fzero, 0, 0, 0);
    }
    #pragma unroll
    for(int nf = 0; nf < 2; ++nf){
      #pragma unroll
      for(int mi = 0; mi < 4; ++mi){
        const float4 bv = *reinterpret_cast<const float4*>(
            bias_pk + (size_t)((((head*5 + ch)*2 + nf)*4 + mi)*64 + lane)*4);
        const float* bvp = reinterpret_cast<const float*>(&bv);
        #pragma unroll
        for(int r = 0; r < 4; ++r)
          Pl[mi*16 + g*4 + r][nf*16 + col] = f2bf(s[mi][nf][r]*scale + bvp[r]);
      }
    }
    bf16x8 pa[4];
    #pragma unroll
    for(int mi = 0; mi < 4; ++mi)
      pa[mi] = *reinterpret_cast<const bf16x8*>(&Pl[mi*16 + col][g*8]);
    #pragma unroll
    for(int nf = 0; nf < 2; ++nf){
      const bf16x8 vfr = *reinterpret_cast<const bf16x8*>(&Vt[nf*16 + col][ch*32 + g*8]);
      #pragma unroll
      for(int mi = 0; mi < 4; ++mi)
        oacc[mi][nf] = __builtin_amdgcn_mfma_f32_16x16x32_bf16(pa[mi], vfr, oacc[mi][nf], 0, 0, 0);
    }
  }
  // epilogue: x1 = O + shortcut -> d_out (fp32)
  #pragma unroll
  for(int mi = 0; mi < 4; ++mi){
    #pragma unroll
    for(int nf = 0; nf < 2; ++nf){
      #pragma unroll
      for(int r = 0; r < 4; ++r){
        const int row = mi*16 + g*4 + r;
        const int hh = h0 + (row >> 3), wp = w0 + (row & 7);
        const size_t o = (tokbase + hh*128 + wp)*(size_t)C + head*32 + nf*16 + col;
        out[o] = oacc[mi][nf][r] + x[o];
      }
    }
  }
}

// ---------------- LN2 + FC1 + GELU + FC2 + residual, in-place on d_out ----------------
// 64 tokens/block, 8 waves (wm2 x wn4), hid in 2 halves; packed coalesced weights.
__global__ __launch_bounds__(512, 4)
void mlp_kernel(float* __restrict__ io,
                const float* __restrict__ g2,
                const float* __restrict__ b2,
                const u16* __restrict__ w1P,
                const float* __restrict__ fb1,  // [384]
                const u16* __restrict__ w2P,
                const float* __restrict__ fb2){ // [192]
  __shared__ u16 xn[64][200];
  __shared__ u16 hl[64][200];
  const int tid = threadIdx.x;
  const size_t tok0 = (size_t)blockIdx.x * 64;
  {
    const int trow = tid >> 3;   // 0..63
    const int j = tid & 7;       // 0..7
    const float* xr = io + (tok0 + trow)*C;
    float4 xv[6];
    #pragma unroll
    for(int u = 0; u < 6; ++u)
      xv[u] = *reinterpret_cast<const float4*>(xr + u*32 + j*4);
    float s1 = 0.f, s2 = 0.f;
    #pragma unroll
    for(int u = 0; u < 6; ++u){
      const float* f = reinterpret_cast<const float*>(&xv[u]);
      #pragma unroll
      for(int e = 0; e < 4; ++e){ s1 += f[e]; s2 += f[e]*f[e]; }
    }
    s1 += __shfl_xor(s1, 1, 64); s2 += __shfl_xor(s2, 1, 64);
    s1 += __shfl_xor(s1, 2, 64); s2 += __shfl_xor(s2, 2, 64);
    s1 += __shfl_xor(s1, 4, 64); s2 += __shfl_xor(s2, 4, 64);
    const float mean = s1 * (1.f/192.f);
    const float rstd = rsqrtf(s2*(1.f/192.f) - mean*mean + 1e-5f);
    #pragma unroll
    for(int u = 0; u < 6; ++u){
      const float4 gv = *reinterpret_cast<const float4*>(g2 + u*32 + j*4);
      const float4 bv = *reinterpret_cast<const float4*>(b2 + u*32 + j*4);
      const float* f = reinterpret_cast<const float*>(&xv[u]);
      const float* gp = reinterpret_cast<const float*>(&gv);
      const float* bp = reinterpret_cast<const float*>(&bv);
      u16x4 pk;
      #pragma unroll
      for(int e = 0; e < 4; ++e) pk[e] = f2bf((f[e] - mean)*rstd*gp[e] + bp[e]);
      *reinterpret_cast<u16x4*>(&xn[trow][u*32 + j*4]) = pk;
    }
  }
  __syncthreads();
  const int lane = tid & 63, wave = tid >> 6;
  const int wm = wave >> 2;       // 0..1 : 32-row stripe
  const int wn = wave & 3;        // 0..3 : 48-col stripe
  const int g = lane >> 4, col = lane & 15;
  const f32x4 fzero = {0.f, 0.f, 0.f, 0.f};
  f32x4 acc2[2][3];
  #pragma unroll
  for(int mi = 0; mi < 2; ++mi)
    #pragma unroll
    for(int nf = 0; nf < 3; ++nf) acc2[mi][nf] = fzero;
  #pragma unroll
  for(int hb = 0; hb < 2; ++hb){
    f32x4 acc1[2][3];
    #pragma unroll
    for(int mi = 0; mi < 2; ++mi)
      #pragma unroll
      for(int nf = 0; nf < 3; ++nf) acc1[mi][nf] = fzero;
    #pragma unroll
    for(int ks = 0; ks < 6; ++ks){
      bf16x8 wf[3];
      #pragma unroll
      for(int nf = 0; nf < 3; ++nf)
        wf[nf] = *reinterpret_cast<const bf16x8*>(w1P + ((size_t)(((hb*12 + wn*3 + nf)*6 + ks)*64) + lane)*8);
      bf16x8 a[2];
      #pragma unroll
      for(int mi = 0; mi < 2; ++mi)
        a[mi] = *reinterpret_cast<const bf16x8*>(&xn[wm*32 + mi*16 + col][ks*32 + g*8]);
      #pragma unroll
      for(int nf = 0; nf < 3; ++nf)
        #pragma unroll
        for(int mi = 0; mi < 2; ++mi)
          acc1[mi][nf] = __builtin_amdgcn_mfma_f32_16x16x32_bf16(a[mi], wf[nf], acc1[mi][nf], 0, 0, 0);
    }
    #pragma unroll
    for(int mi = 0; mi < 2; ++mi){
      #pragma unroll
      for(int nf = 0; nf < 3; ++nf){
        const int nl = wn*48 + nf*16 + col;
        const float bb = fb1[hb*192 + nl];
        #pragma unroll
        for(int r = 0; r < 4; ++r){
          const int row = wm*32 + mi*16 + g*4 + r;
          hl[row][nl] = f2bf(gelu(acc1[mi][nf][r] + bb));
        }
      }
    }
    __syncthreads();   // hl half ready
    #pragma unroll
    for(int ks = 0; ks < 6; ++ks){
      bf16x8 wf[3];
      #pragma unroll
      for(int nf = 0; nf < 3; ++nf)
        wf[nf] = *reinterpret_cast<const bf16x8*>(w2P + ((size_t)(((wn*3 + nf)*12 + hb*6 + ks)*64) + lane)*8);
      bf16x8 a[2];
      #pragma unroll
      for(int mi = 0; mi < 2; ++mi)
        a[mi] = *reinterpret_cast<const bf16x8*>(&hl[wm*32 + mi*16 + col][ks*32 + g*8]);
      #pragma unroll
      for(int nf = 0; nf < 3; ++nf)
        #pragma unroll
        for(int mi = 0; mi < 2; ++mi)
          acc2[mi][nf] = __builtin_amdgcn_mfma_f32_16x16x32_bf16(a[mi], wf[nf], acc2[mi][nf], 0, 0, 0);
    }
    __syncthreads();   // hl consumed; safe to overwrite next half
  }
  #pragma unroll
  for(int mi = 0; mi < 2; ++mi){
    #pragma unroll
    for(int nf = 0; nf < 3; ++nf){
      const int n = wn*48 + nf*16 + col;
      const float bb = fb2[n];
      #pragma unroll
      for(int r = 0; r < 4; ++r){
        const int row = wm*32 + mi*16 + g*4 + r;
        const size_t idx = (tok0 + row)*C + n;
        io[idx] = acc2[mi][nf][r] + bb + io[idx];   // + residual x1
      }
    }
  }
}

extern "C" void kernel_launch(void* const* d_in, const int* in_sizes, int n_in,
                              void* d_out, int out_size, void* d_ws, size_t ws_size,
                              hipStream_t stream){
  const float* x    = (const float*)d_in[0];
  const int*   rpi  = (const int*)  d_in[2];
  const float* n1g  = (const float*)d_in[3];
  const float* n1b  = (const float*)d_in[4];
  const float* qkvw = (const float*)d_in[5];
  const float* qkvb = (const float*)d_in[6];
  const float* rpb  = (const float*)d_in[7];
  const float* n2g  = (const float*)d_in[8];
  const float* n2b  = (const float*)d_in[9];
  const float* fc1w = (const float*)d_in[10];
  const float* fc1b = (const float*)d_in[11];
  const float* fc2w = (const float*)d_in[12];
  const float* fc2b = (const float*)d_in[13];
  float* out = (float*)d_out;
  char* ws = (char*)d_ws;
  u16*   qkvP    = (u16*)  (ws + 0);          // 110592*2    = 221184
  u16*   fc1P    = (u16*)  (ws + 221184);     // 73728*2     = 147456
  u16*   fc2P    = (u16*)  (ws + 368640);     // 73728*2     = 147456
  float* bias_pk = (float*)(ws + 516096);     // 245760*4    = 983040
  u16*   qkvbuf  = (u16*)  (ws + 1499136);    // 18*131072*32*2 = 150994944 (head-planar)
  if(ws_size < 152494080ull) return;
  prep_kernel<<<dim3(512), dim3(256), 0, stream>>>(qkvw, fc1w, fc2w, rpi, rpb, qkvP, fc1P, fc2P, bias_pk);
  qkv_kernel<<<dim3(2048), dim3(384), 0, stream>>>(x, n1g, n1b, qkvP, qkvb, qkvbuf);
  attn_kernel<<<dim3(2048, 6), dim3(64), 0, stream>>>(qkvbuf, bias_pk, x, out);
  mlp_kernel<<<dim3(2048), dim3(512), 0, stream>>>(out, n2g, n2b, fc1P, fc1b, fc2P, fc2b);
}

// Round 4
// 287.620 us; speedup vs baseline: 1.6564x; 1.0499x over previous
//
#include <hip/hip_runtime.h>
#include <cstdint>
#include <cstddef>

typedef short bf16x8 __attribute__((ext_vector_type(8)));
typedef unsigned short u16x4 __attribute__((ext_vector_type(4)));
typedef float f32x4  __attribute__((ext_vector_type(4)));
typedef unsigned short u16;

#define DEVI __device__ __forceinline__

constexpr int C     = 192;
constexpr int HEADS = 6;
constexpr int NQKV  = 576;   // 3*C
constexpr int HID   = 384;   // 2*C
constexpr int NTOK  = 131072;

DEVI u16 f2bf(float f){
  union { float f; unsigned u; } v; v.f = f;
  return (u16)((v.u + 0x7fffu + ((v.u >> 16) & 1u)) >> 16);
}

// exact-enough GELU: A&S 7.1.26 erf (max abs err 1.5e-7), branchless
DEVI float gelu(float xx){
  float y  = xx * 0.70710678118654752f;
  float ay = fabsf(y);
  float t  = __builtin_amdgcn_rcpf(1.0f + 0.3275911f * ay);
  float p  = t*(0.254829592f + t*(-0.284496736f + t*(1.421413741f + t*(-1.453152027f + t*1.061405429f))));
  float e  = __expf(-(y*y));
  float er = copysignf(1.0f - p*e, y);
  return 0.5f * xx * (1.0f + er);
}

// ---------------- prep: fragment-packed weights + packed bias table ----------------
// packed layout: [(panel*KS + ks)][lane][8e] ; value = W[k = ks*32 + (lane>>4)*8 + e][n = panel*16 + (lane&15)]
__global__ void prep_kernel(const float* __restrict__ qkv_w,
                            const float* __restrict__ fc1_w,
                            const float* __restrict__ fc2_w,
                            const int*   __restrict__ rpi,
                            const float* __restrict__ rpb,
                            u16* __restrict__ qkvP,
                            u16* __restrict__ fc1P,
                            u16* __restrict__ fc2P,
                            float* __restrict__ bias_pk){
  int idx = blockIdx.x * blockDim.x + threadIdx.x;
  int stride = gridDim.x * blockDim.x;
  // qkvP: 36 panels x 6 ks
  for(int i = idx; i < 36*6*64*8; i += stride){
    int e = i & 7, lane = (i >> 3) & 63, t = i >> 9;
    int ks = t % 6, p = t / 6;
    int n = p*16 + (lane & 15), k = ks*32 + (lane >> 4)*8 + e;
    qkvP[i] = f2bf(qkv_w[k*NQKV + n]);
  }
  // fc1P: 24 panels x 6 ks
  for(int i = idx; i < 24*6*64*8; i += stride){
    int e = i & 7, lane = (i >> 3) & 63, t = i >> 9;
    int ks = t % 6, p = t / 6;
    int n = p*16 + (lane & 15), k = ks*32 + (lane >> 4)*8 + e;
    fc1P[i] = f2bf(fc1_w[k*HID + n]);
  }
  // fc2P: 12 panels x 12 ks
  for(int i = idx; i < 12*12*64*8; i += stride){
    int e = i & 7, lane = (i >> 3) & 63, t = i >> 9;
    int ks = t % 12, p = t / 12;
    int n = p*16 + (lane & 15), k = ks*32 + (lane >> 4)*8 + e;
    fc2P[i] = f2bf(fc2_w[k*C + n]);
  }
  // bias_pk: [head][chunk5][nf2][mi4][lane64][reg4]
  const int n4 = HEADS*5*2*4*64*4;
  for(int i = idx; i < n4; i += stride){
    int t = i;
    int r    = t & 3;  t >>= 2;
    int lane = t & 63; t >>= 6;
    int mi   = t & 3;  t >>= 2;
    int nf   = t & 1;  t >>= 1;
    int chunk = t % 5; int head = t / 5;
    int g = lane >> 4, col = lane & 15;
    int q  = mi*16 + g*4 + r;
    int kk = chunk*32 + nf*16 + col;
    float v = 0.f;
    if(kk < 144) v = rpb[rpi[q*144 + kk]*HEADS + head];
    bias_pk[i] = v;
  }
}

// ---------------- LN1 + QKV GEMM -> head-planar qkv bf16 [18 planes][131072][32] ----------------
// 4096 blocks: (2048 token-groups) x (2 n-halves of 288 cols). 6 waves, per-wave 64x48 -> acc[4][3].
__global__ __launch_bounds__(384, 4)
void qkv_kernel(const float* __restrict__ x,
                const float* __restrict__ g1,
                const float* __restrict__ b1,
                const u16* __restrict__ wP,     // fragment-packed qkv weights
                const float* __restrict__ qb,   // [576]
                u16* __restrict__ qkv){         // head-planar
  __shared__ u16 xn[64][200];
  __shared__ u16 rp[64][152];
  const int tid = threadIdx.x;
  const int bid = blockIdx.x;
  const int nh = (bid >> 3) & 1;                        // n-half 0/1
  const int tb = (bid & 7) + ((bid >> 4) << 3);         // token group 0..2047 (pairs same XCD)
  const size_t tok0 = (size_t)tb * 64;
  if(tid < 256){
    const int trow = tid >> 2;   // 0..63
    const int j = tid & 3;       // 0..3
    const float* xr = x + (tok0 + trow)*C;
    float4 xv[12];
    #pragma unroll
    for(int u = 0; u < 12; ++u)
      xv[u] = *reinterpret_cast<const float4*>(xr + u*16 + j*4);   // 64B per 4-lane quad
    float s1 = 0.f, s2 = 0.f;
    #pragma unroll
    for(int u = 0; u < 12; ++u){
      const float* f = reinterpret_cast<const float*>(&xv[u]);
      #pragma unroll
      for(int e = 0; e < 4; ++e){ s1 += f[e]; s2 += f[e]*f[e]; }
    }
    s1 += __shfl_xor(s1, 1, 64); s2 += __shfl_xor(s2, 1, 64);
    s1 += __shfl_xor(s1, 2, 64); s2 += __shfl_xor(s2, 2, 64);
    const float mean = s1 * (1.f/192.f);
    const float rstd = rsqrtf(s2*(1.f/192.f) - mean*mean + 1e-5f);
    #pragma unroll
    for(int u = 0; u < 12; ++u){
      const float4 gv = *reinterpret_cast<const float4*>(g1 + u*16 + j*4);
      const float4 bv = *reinterpret_cast<const float4*>(b1 + u*16 + j*4);
      const float* f = reinterpret_cast<const float*>(&xv[u]);
      const float* gp = reinterpret_cast<const float*>(&gv);
      const float* bp = reinterpret_cast<const float*>(&bv);
      u16x4 pk;
      #pragma unroll
      for(int e = 0; e < 4; ++e) pk[e] = f2bf((f[e] - mean)*rstd*gp[e] + bp[e]);
      *reinterpret_cast<u16x4*>(&xn[trow][u*16 + j*4]) = pk;
    }
  }
  __syncthreads();
  const int lane = tid & 63;
  const int wn = tid >> 6;      // 0..5 : 48-col stripe within this 288-col half
  const int g = lane >> 4, col = lane & 15;
  const f32x4 fzero = {0.f, 0.f, 0.f, 0.f};
  f32x4 acc[4][3];
  #pragma unroll
  for(int mi = 0; mi < 4; ++mi)
    #pragma unroll
    for(int nf = 0; nf < 3; ++nf) acc[mi][nf] = fzero;
  const int p0 = nh*18 + wn*3;  // first 16-col panel of this wave
  #pragma unroll
  for(int ks = 0; ks < 6; ++ks){
    bf16x8 wf[3];
    #pragma unroll
    for(int nf = 0; nf < 3; ++nf)
      wf[nf] = *reinterpret_cast<const bf16x8*>(wP + ((size_t)(((p0 + nf)*6 + ks)*64) + lane)*8);
    bf16x8 a[4];
    #pragma unroll
    for(int mi = 0; mi < 4; ++mi)
      a[mi] = *reinterpret_cast<const bf16x8*>(&xn[mi*16 + col][ks*32 + g*8]);
    #pragma unroll
    for(int nf = 0; nf < 3; ++nf)
      #pragma unroll
      for(int mi = 0; mi < 4; ++mi)
        acc[mi][nf] = __builtin_amdgcn_mfma_f32_16x16x32_bf16(a[mi], wf[nf], acc[mi][nf], 0, 0, 0);
  }
  // epilogue: 2 phases x 144 cols; 3 waves fill rp, all 384 threads store coalesced
  #pragma unroll
  for(int ph = 0; ph < 2; ++ph){
    if((wn >> 1) + (wn >> 2) == ph*2 ? false : true){}   // (no-op; keep structure simple below)
    if(wn >= ph*3 && wn < ph*3 + 3){
      const int wl = wn - ph*3;
      #pragma unroll
      for(int mi = 0; mi < 4; ++mi){
        #pragma unroll
        for(int nf = 0; nf < 3; ++nf){
          const int nloc = wl*48 + nf*16 + col;                 // 0..143 within phase
          const float bb = qb[nh*288 + ph*144 + nloc];
          #pragma unroll
          for(int r = 0; r < 4; ++r)
            rp[mi*16 + g*4 + r][nloc] = f2bf(acc[mi][nf][r] + bb);
        }
      }
    }
    __syncthreads();     // rp phase ready
    #pragma unroll
    for(int it = 0; it < 3; ++it){
      const int c = tid + it*384;        // 0..1151 : (tok 0..63) x (chunk cc 0..17)
      const int tok = c / 18, cc = c - tok*18;
      const int n0 = nh*288 + ph*144 + cc*8;
      const int pl = n0 >> 5, d0 = n0 & 31;
      bf16x8 vv = *reinterpret_cast<const bf16x8*>(&rp[tok][cc*8]);
      *reinterpret_cast<bf16x8*>(qkv + ((size_t)pl*NTOK + tok0 + tok)*32 + d0) = vv;
    }
    __syncthreads();     // rp consumed
  }
}

// ---------------- windowed attention (no softmax): per (window, head), head-planar input ----------------
__global__ __launch_bounds__(64, 2)
void attn_kernel(const u16* __restrict__ qkv,   // [18][131072][32]
                 const float* __restrict__ bias_pk,
                 const float* __restrict__ x,
                 float* __restrict__ out){
  __shared__ u16 Vt[32][168];   // V^T: d x 160 (+pad)
  __shared__ u16 Pl[64][40];    // P chunk: 64 q-rows x 32 kv-cols (+pad)
  const int lane = threadIdx.x;
  const int g = lane >> 4, col = lane & 15;
  const int win = blockIdx.x, head = blockIdx.y;
  const int bt = win >> 8, wh = (win >> 4) & 15, ww = win & 15;
  const int h0 = wh*8, w0 = ww*8;
  const size_t tokbase = (size_t)bt * 16384;
  const u16* Qp = qkv + (size_t)head      *NTOK*32;
  const u16* Kp = qkv + (size_t)(6 + head)*NTOK*32;
  const u16* Vp = qkv + (size_t)(12 + head)*NTOK*32;
  // K fragments direct to registers (staging pattern == fragment pattern); V -> LDS transpose
  bf16x8 kf[10];
  #pragma unroll
  for(int i = 0; i < 10; ++i){
    const int kr = i*16 + col;
    const int r12 = (kr*2731) >> 15;       // kr/12
    const int c12 = kr - r12*12;
    const int hh = h0 - 2 + r12;
    const int wp = w0 - 2 + c12;
    bf16x8 kv_ = {0,0,0,0,0,0,0,0};
    bf16x8 vv_ = {0,0,0,0,0,0,0,0};
    if(kr < 144 && hh >= 0 && hh < 128 && wp >= 0 && wp < 128){
      const size_t t = tokbase + hh*128 + wp;
      kv_ = *reinterpret_cast<const bf16x8*>(Kp + t*32 + g*8);
      vv_ = *reinterpret_cast<const bf16x8*>(Vp + t*32 + g*8);
    }
    kf[i] = kv_;
    #pragma unroll
    for(int e = 0; e < 8; ++e) Vt[g*8 + e][kr] = (u16)vv_[e];
  }
  bf16x8 qf[4];
  #pragma unroll
  for(int mi = 0; mi < 4; ++mi){
    const int row = mi*16 + col;
    const size_t t = tokbase + (size_t)(h0 + (row >> 3))*128 + w0 + (row & 7);
    qf[mi] = *reinterpret_cast<const bf16x8*>(Qp + t*32 + g*8);
  }
  const f32x4 fzero = {0.f, 0.f, 0.f, 0.f};
  f32x4 oacc[4][2];
  #pragma unroll
  for(int mi = 0; mi < 4; ++mi){ oacc[mi][0] = fzero; oacc[mi][1] = fzero; }
  const float scale = 0.17677669529663689f;  // 32^-0.5
  for(int ch = 0; ch < 5; ++ch){
    f32x4 s[4][2];
    #pragma unroll
    for(int nf = 0; nf < 2; ++nf){
      const bf16x8 kk = kf[ch*2 + nf];
      #pragma unroll
      for(int mi = 0; mi < 4; ++mi)
        s[mi][nf] = __builtin_amdgcn_mfma_f32_16x16x32_bf16(qf[mi], kk, fzero, 0, 0, 0);
    }
    #pragma unroll
    for(int nf = 0; nf < 2; ++nf){
      #pragma unroll
      for(int mi = 0; mi < 4; ++mi){
        const float4 bv = *reinterpret_cast<const float4*>(
            bias_pk + (size_t)((((head*5 + ch)*2 + nf)*4 + mi)*64 + lane)*4);
        const float* bvp = reinterpret_cast<const float*>(&bv);
        #pragma unroll
        for(int r = 0; r < 4; ++r)
          Pl[mi*16 + g*4 + r][nf*16 + col] = f2bf(s[mi][nf][r]*scale + bvp[r]);
      }
    }
    bf16x8 pa[4];
    #pragma unroll
    for(int mi = 0; mi < 4; ++mi)
      pa[mi] = *reinterpret_cast<const bf16x8*>(&Pl[mi*16 + col][g*8]);
    #pragma unroll
    for(int nf = 0; nf < 2; ++nf){
      const bf16x8 vfr = *reinterpret_cast<const bf16x8*>(&Vt[nf*16 + col][ch*32 + g*8]);
      #pragma unroll
      for(int mi = 0; mi < 4; ++mi)
        oacc[mi][nf] = __builtin_amdgcn_mfma_f32_16x16x32_bf16(pa[mi], vfr, oacc[mi][nf], 0, 0, 0);
    }
  }
  // epilogue: x1 = O + shortcut -> d_out (fp32)
  #pragma unroll
  for(int mi = 0; mi < 4; ++mi){
    #pragma unroll
    for(int nf = 0; nf < 2; ++nf){
      #pragma unroll
      for(int r = 0; r < 4; ++r){
        const int row = mi*16 + g*4 + r;
        const int hh = h0 + (row >> 3), wp = w0 + (row & 7);
        const size_t o = (tokbase + hh*128 + wp)*(size_t)C + head*32 + nf*16 + col;
        out[o] = oacc[mi][nf][r] + x[o];
      }
    }
  }
}

// ---------------- LN2 + FC1 + GELU + FC2 + residual, in-place on d_out ----------------
// 64 tokens/block, 8 waves (wm2 x wn4), hid in 2 halves; packed coalesced weights.
__global__ __launch_bounds__(512, 4)
void mlp_kernel(float* __restrict__ io,
                const float* __restrict__ g2,
                const float* __restrict__ b2,
                const u16* __restrict__ w1P,
                const float* __restrict__ fb1,  // [384]
                const u16* __restrict__ w2P,
                const float* __restrict__ fb2){ // [192]
  __shared__ u16 xn[64][200];
  __shared__ u16 hl[64][200];
  const int tid = threadIdx.x;
  const size_t tok0 = (size_t)blockIdx.x * 64;
  {
    const int trow = tid >> 3;   // 0..63
    const int j = tid & 7;       // 0..7
    const float* xr = io + (tok0 + trow)*C;
    float4 xv[6];
    #pragma unroll
    for(int u = 0; u < 6; ++u)
      xv[u] = *reinterpret_cast<const float4*>(xr + u*32 + j*4);
    float s1 = 0.f, s2 = 0.f;
    #pragma unroll
    for(int u = 0; u < 6; ++u){
      const float* f = reinterpret_cast<const float*>(&xv[u]);
      #pragma unroll
      for(int e = 0; e < 4; ++e){ s1 += f[e]; s2 += f[e]*f[e]; }
    }
    s1 += __shfl_xor(s1, 1, 64); s2 += __shfl_xor(s2, 1, 64);
    s1 += __shfl_xor(s1, 2, 64); s2 += __shfl_xor(s2, 2, 64);
    s1 += __shfl_xor(s1, 4, 64); s2 += __shfl_xor(s2, 4, 64);
    const float mean = s1 * (1.f/192.f);
    const float rstd = rsqrtf(s2*(1.f/192.f) - mean*mean + 1e-5f);
    #pragma unroll
    for(int u = 0; u < 6; ++u){
      const float4 gv = *reinterpret_cast<const float4*>(g2 + u*32 + j*4);
      const float4 bv = *reinterpret_cast<const float4*>(b2 + u*32 + j*4);
      const float* f = reinterpret_cast<const float*>(&xv[u]);
      const float* gp = reinterpret_cast<const float*>(&gv);
      const float* bp = reinterpret_cast<const float*>(&bv);
      u16x4 pk;
      #pragma unroll
      for(int e = 0; e < 4; ++e) pk[e] = f2bf((f[e] - mean)*rstd*gp[e] + bp[e]);
      *reinterpret_cast<u16x4*>(&xn[trow][u*32 + j*4]) = pk;
    }
  }
  __syncthreads();
  const int lane = tid & 63, wave = tid >> 6;
  const int wm = wave >> 2;       // 0..1 : 32-row stripe
  const int wn = wave & 3;        // 0..3 : 48-col stripe
  const int g = lane >> 4, col = lane & 15;
  const f32x4 fzero = {0.f, 0.f, 0.f, 0.f};
  f32x4 acc2[2][3];
  #pragma unroll
  for(int mi = 0; mi < 2; ++mi)
    #pragma unroll
    for(int nf = 0; nf < 3; ++nf) acc2[mi][nf] = fzero;
  #pragma unroll
  for(int hb = 0; hb < 2; ++hb){
    f32x4 acc1[2][3];
    #pragma unroll
    for(int mi = 0; mi < 2; ++mi)
      #pragma unroll
      for(int nf = 0; nf < 3; ++nf) acc1[mi][nf] = fzero;
    #pragma unroll
    for(int ks = 0; ks < 6; ++ks){
      bf16x8 wf[3];
      #pragma unroll
      for(int nf = 0; nf < 3; ++nf)
        wf[nf] = *reinterpret_cast<const bf16x8*>(w1P + ((size_t)(((hb*12 + wn*3 + nf)*6 + ks)*64) + lane)*8);
      bf16x8 a[2];
      #pragma unroll
      for(int mi = 0; mi < 2; ++mi)
        a[mi] = *reinterpret_cast<const bf16x8*>(&xn[wm*32 + mi*16 + col][ks*32 + g*8]);
      #pragma unroll
      for(int nf = 0; nf < 3; ++nf)
        #pragma unroll
        for(int mi = 0; mi < 2; ++mi)
          acc1[mi][nf] = __builtin_amdgcn_mfma_f32_16x16x32_bf16(a[mi], wf[nf], acc1[mi][nf], 0, 0, 0);
    }
    #pragma unroll
    for(int mi = 0; mi < 2; ++mi){
      #pragma unroll
      for(int nf = 0; nf < 3; ++nf){
        const int nl = wn*48 + nf*16 + col;
        const float bb = fb1[hb*192 + nl];
        #pragma unroll
        for(int r = 0; r < 4; ++r){
          const int row = wm*32 + mi*16 + g*4 + r;
          hl[row][nl] = f2bf(gelu(acc1[mi][nf][r] + bb));
        }
      }
    }
    __syncthreads();   // hl half ready
    #pragma unroll
    for(int ks = 0; ks < 6; ++ks){
      bf16x8 wf[3];
      #pragma unroll
      for(int nf = 0; nf < 3; ++nf)
        wf[nf] = *reinterpret_cast<const bf16x8*>(w2P + ((size_t)(((wn*3 + nf)*12 + hb*6 + ks)*64) + lane)*8);
      bf16x8 a[2];
      #pragma unroll
      for(int mi = 0; mi < 2; ++mi)
        a[mi] = *reinterpret_cast<const bf16x8*>(&hl[wm*32 + mi*16 + col][ks*32 + g*8]);
      #pragma unroll
      for(int nf = 0; nf < 3; ++nf)
        #pragma unroll
        for(int mi = 0; mi < 2; ++mi)
          acc2[mi][nf] = __builtin_amdgcn_mfma_f32_16x16x32_bf16(a[mi], wf[nf], acc2[mi][nf], 0, 0, 0);
    }
    __syncthreads();   // hl consumed; safe to overwrite next half
  }
  #pragma unroll
  for(int mi = 0; mi < 2; ++mi){
    #pragma unroll
    for(int nf = 0; nf < 3; ++nf){
      const int n = wn*48 + nf*16 + col;
      const float bb = fb2[n];
      #pragma unroll
      for(int r = 0; r < 4; ++r){
        const int row = wm*32 + mi*16 + g*4 + r;
        const size_t idx = (tok0 + row)*C + n;
        io[idx] = acc2[mi][nf][r] + bb + io[idx];   // + residual x1
      }
    }
  }
}

extern "C" void kernel_launch(void* const* d_in, const int* in_sizes, int n_in,
                              void* d_out, int out_size, void* d_ws, size_t ws_size,
                              hipStream_t stream){
  const float* x    = (const float*)d_in[0];
  const int*   rpi  = (const int*)  d_in[2];
  const float* n1g  = (const float*)d_in[3];
  const float* n1b  = (const float*)d_in[4];
  const float* qkvw = (const float*)d_in[5];
  const float* qkvb = (const float*)d_in[6];
  const float* rpb  = (const float*)d_in[7];
  const float* n2g  = (const float*)d_in[8];
  const float* n2b  = (const float*)d_in[9];
  const float* fc1w = (const float*)d_in[10];
  const float* fc1b = (const float*)d_in[11];
  const float* fc2w = (const float*)d_in[12];
  const float* fc2b = (const float*)d_in[13];
  float* out = (float*)d_out;
  char* ws = (char*)d_ws;
  u16*   qkvP    = (u16*)  (ws + 0);          // 110592*2    = 221184
  u16*   fc1P    = (u16*)  (ws + 221184);     // 73728*2     = 147456
  u16*   fc2P    = (u16*)  (ws + 368640);     // 73728*2     = 147456
  float* bias_pk = (float*)(ws + 516096);     // 245760*4    = 983040
  u16*   qkvbuf  = (u16*)  (ws + 1499136);    // 18*131072*32*2 = 150994944 (head-planar)
  if(ws_size < 152494080ull) return;
  prep_kernel<<<dim3(512), dim3(256), 0, stream>>>(qkvw, fc1w, fc2w, rpi, rpb, qkvP, fc1P, fc2P, bias_pk);
  qkv_kernel<<<dim3(4096), dim3(384), 0, stream>>>(x, n1g, n1b, qkvP, qkvb, qkvbuf);
  attn_kernel<<<dim3(2048, 6), dim3(64), 0, stream>>>(qkvbuf, bias_pk, x, out);
  mlp_kernel<<<dim3(2048), dim3(512), 0, stream>>>(out, n2g, n2b, fc1P, fc1b, fc2P, fc2b);
}

// Round 6
// 280.841 us; speedup vs baseline: 1.6964x; 1.0241x over previous
//
#include <hip/hip_runtime.h>
#include <cstdint>
#include <cstddef>

typedef short bf16x8 __attribute__((ext_vector_type(8)));
typedef unsigned short u16x4 __attribute__((ext_vector_type(4)));
typedef float f32x4  __attribute__((ext_vector_type(4)));
typedef unsigned short u16;

#define DEVI __device__ __forceinline__

constexpr int C     = 192;
constexpr int HEADS = 6;
constexpr int NQKV  = 576;   // 3*C
constexpr int HID   = 384;   // 2*C
constexpr int NTOK  = 131072;

DEVI u16 f2bf(float f){
  union { float f; unsigned u; } v; v.f = f;
  return (u16)((v.u + 0x7fffu + ((v.u >> 16) & 1u)) >> 16);
}

// exact-enough GELU: A&S 7.1.26 erf (max abs err 1.5e-7), branchless
DEVI float gelu(float xx){
  float y  = xx * 0.70710678118654752f;
  float ay = fabsf(y);
  float t  = __builtin_amdgcn_rcpf(1.0f + 0.3275911f * ay);
  float p  = t*(0.254829592f + t*(-0.284496736f + t*(1.421413741f + t*(-1.453152027f + t*1.061405429f))));
  float e  = __expf(-(y*y));
  float er = copysignf(1.0f - p*e, y);
  return 0.5f * xx * (1.0f + er);
}

// ---------------- prep: fragment-packed weights + packed bias table (SWAPPED layout) ----------------
__global__ void prep_kernel(const float* __restrict__ qkv_w,
                            const float* __restrict__ fc1_w,
                            const float* __restrict__ fc2_w,
                            const int*   __restrict__ rpi,
                            const float* __restrict__ rpb,
                            u16* __restrict__ qkvP,
                            u16* __restrict__ fc1P,
                            u16* __restrict__ fc2P,
                            float* __restrict__ bias_pk){
  int idx = blockIdx.x * blockDim.x + threadIdx.x;
  int stride = gridDim.x * blockDim.x;
  // qkvP: 36 panels x 6 ks
  for(int i = idx; i < 36*6*64*8; i += stride){
    int e = i & 7, lane = (i >> 3) & 63, t = i >> 9;
    int ks = t % 6, p = t / 6;
    int n = p*16 + (lane & 15), k = ks*32 + (lane >> 4)*8 + e;
    qkvP[i] = f2bf(qkv_w[k*NQKV + n]);
  }
  // fc1P: 24 panels x 6 ks
  for(int i = idx; i < 24*6*64*8; i += stride){
    int e = i & 7, lane = (i >> 3) & 63, t = i >> 9;
    int ks = t % 6, p = t / 6;
    int n = p*16 + (lane & 15), k = ks*32 + (lane >> 4)*8 + e;
    fc1P[i] = f2bf(fc1_w[k*HID + n]);
  }
  // fc2P: 12 panels x 12 ks
  for(int i = idx; i < 12*12*64*8; i += stride){
    int e = i & 7, lane = (i >> 3) & 63, t = i >> 9;
    int ks = t % 12, p = t / 12;
    int n = p*16 + (lane & 15), k = ks*32 + (lane >> 4)*8 + e;
    fc2P[i] = f2bf(fc2_w[k*C + n]);
  }
  // bias_pk (swapped-QK layout): [head][chunk5][nf2][mi4][lane64][r4]
  // value = bias[q = mi*16 + (lane&15)][kk = chunk*32 + nf*16 + (lane>>4)*4 + r]
  const int n4 = HEADS*5*2*4*64*4;
  for(int i = idx; i < n4; i += stride){
    int t = i;
    int r    = t & 3;  t >>= 2;
    int lane = t & 63; t >>= 6;
    int mi   = t & 3;  t >>= 2;
    int nf   = t & 1;  t >>= 1;
    int chunk = t % 5; int head = t / 5;
    int q  = mi*16 + (lane & 15);
    int kk = chunk*32 + nf*16 + ((lane >> 4) << 2) + r;
    float v = 0.f;
    if(kk < 144) v = rpb[rpi[q*144 + kk]*HEADS + head];
    bias_pk[i] = v;
  }
}

// ---------------- LN1 + QKV GEMM -> head-planar qkv bf16 [18 planes][131072][32] ----------------
__global__ __launch_bounds__(384, 4)
void qkv_kernel(const float* __restrict__ x,
                const float* __restrict__ g1,
                const float* __restrict__ b1,
                const u16* __restrict__ wP,
                const float* __restrict__ qb,
                u16* __restrict__ qkv){
  __shared__ u16 xn[64][200];
  __shared__ u16 rp[64][152];
  const int tid = threadIdx.x;
  const int bid = blockIdx.x;
  const int nh = (bid >> 3) & 1;
  const int tb = (bid & 7) + ((bid >> 4) << 3);
  const size_t tok0 = (size_t)tb * 64;
  if(tid < 256){
    const int trow = tid >> 2;
    const int j = tid & 3;
    const float* xr = x + (tok0 + trow)*C;
    float4 xv[12];
    #pragma unroll
    for(int u = 0; u < 12; ++u)
      xv[u] = *reinterpret_cast<const float4*>(xr + u*16 + j*4);
    float s1 = 0.f, s2 = 0.f;
    #pragma unroll
    for(int u = 0; u < 12; ++u){
      const float* f = reinterpret_cast<const float*>(&xv[u]);
      #pragma unroll
      for(int e = 0; e < 4; ++e){ s1 += f[e]; s2 += f[e]*f[e]; }
    }
    s1 += __shfl_xor(s1, 1, 64); s2 += __shfl_xor(s2, 1, 64);
    s1 += __shfl_xor(s1, 2, 64); s2 += __shfl_xor(s2, 2, 64);
    const float mean = s1 * (1.f/192.f);
    const float rstd = rsqrtf(s2*(1.f/192.f) - mean*mean + 1e-5f);
    #pragma unroll
    for(int u = 0; u < 12; ++u){
      const float4 gv = *reinterpret_cast<const float4*>(g1 + u*16 + j*4);
      const float4 bv = *reinterpret_cast<const float4*>(b1 + u*16 + j*4);
      const float* f = reinterpret_cast<const float*>(&xv[u]);
      const float* gp = reinterpret_cast<const float*>(&gv);
      const float* bp = reinterpret_cast<const float*>(&bv);
      u16x4 pk;
      #pragma unroll
      for(int e = 0; e < 4; ++e) pk[e] = f2bf((f[e] - mean)*rstd*gp[e] + bp[e]);
      *reinterpret_cast<u16x4*>(&xn[trow][u*16 + j*4]) = pk;
    }
  }
  __syncthreads();
  const int lane = tid & 63;
  const int wn = tid >> 6;
  const int g = lane >> 4, col = lane & 15;
  const f32x4 fzero = {0.f, 0.f, 0.f, 0.f};
  f32x4 acc[4][3];
  #pragma unroll
  for(int mi = 0; mi < 4; ++mi)
    #pragma unroll
    for(int nf = 0; nf < 3; ++nf) acc[mi][nf] = fzero;
  const int p0 = nh*18 + wn*3;
  #pragma unroll
  for(int ks = 0; ks < 6; ++ks){
    bf16x8 wf[3];
    #pragma unroll
    for(int nf = 0; nf < 3; ++nf)
      wf[nf] = *reinterpret_cast<const bf16x8*>(wP + ((size_t)(((p0 + nf)*6 + ks)*64) + lane)*8);
    bf16x8 a[4];
    #pragma unroll
    for(int mi = 0; mi < 4; ++mi)
      a[mi] = *reinterpret_cast<const bf16x8*>(&xn[mi*16 + col][ks*32 + g*8]);
    #pragma unroll
    for(int nf = 0; nf < 3; ++nf)
      #pragma unroll
      for(int mi = 0; mi < 4; ++mi)
        acc[mi][nf] = __builtin_amdgcn_mfma_f32_16x16x32_bf16(a[mi], wf[nf], acc[mi][nf], 0, 0, 0);
  }
  #pragma unroll
  for(int ph = 0; ph < 2; ++ph){
    if(wn >= ph*3 && wn < ph*3 + 3){
      const int wl = wn - ph*3;
      #pragma unroll
      for(int mi = 0; mi < 4; ++mi){
        #pragma unroll
        for(int nf = 0; nf < 3; ++nf){
          const int nloc = wl*48 + nf*16 + col;
          const float bb = qb[nh*288 + ph*144 + nloc];
          #pragma unroll
          for(int r = 0; r < 4; ++r)
            rp[mi*16 + g*4 + r][nloc] = f2bf(acc[mi][nf][r] + bb);
        }
      }
    }
    __syncthreads();
    #pragma unroll
    for(int it = 0; it < 3; ++it){
      const int c = tid + it*384;
      const int tok = c / 18, cc = c - tok*18;
      const int n0 = nh*288 + ph*144 + cc*8;
      const int pl = n0 >> 5, d0 = n0 & 31;
      bf16x8 vv = *reinterpret_cast<const bf16x8*>(&rp[tok][cc*8]);
      *reinterpret_cast<bf16x8*>(qkv + ((size_t)pl*NTOK + tok0 + tok)*32 + d0) = vv;
    }
    __syncthreads();
  }
}

// ---------------- windowed attention (no softmax): per (window, head) ----------------
// swapped QK^T (S^T = K·Q^T) with integer-packed P (b64 LDS writes); V via round-4 Vt path.
__global__ __launch_bounds__(64, 2)
void attn_kernel(const u16* __restrict__ qkv,   // [18][131072][32]
                 const float* __restrict__ bias_pk,
                 const float* __restrict__ x,
                 float* __restrict__ out){
  __shared__ u16 Vt[32][168];   // V^T: d x 160 (+pad)
  __shared__ u16 Pl[64][40];    // P chunk [q][kv_local] (+pad)
  const int lane = threadIdx.x;
  const int g = lane >> 4, col = lane & 15;
  const int win = blockIdx.x, head = blockIdx.y;
  const int bt = win >> 8, wh = (win >> 4) & 15, ww = win & 15;
  const int h0 = wh*8, w0 = ww*8;
  const size_t tokbase = (size_t)bt * 16384;
  const u16* Qp = qkv + (size_t)head      *NTOK*32;
  const u16* Kp = qkv + (size_t)(6 + head)*NTOK*32;
  const u16* Vp = qkv + (size_t)(12 + head)*NTOK*32;
  const bf16x8 z8 = {0,0,0,0,0,0,0,0};

  // ---- staging: branchless, all loads issued up front ----
  bf16x8 kf[10], vf[10];
  #pragma unroll
  for(int i = 0; i < 10; ++i){
    const int kr = i*16 + col;
    const int r12 = (kr*2731) >> 15;       // kr/12
    const int c12 = kr - r12*12;
    const int hh = h0 - 2 + r12;
    const int wp = w0 - 2 + c12;
    const bool valid = (kr < 144) && (hh >= 0) && (hh < 128) && (wp >= 0) && (wp < 128);
    const size_t t = valid ? (tokbase + (size_t)hh*128 + wp) : tokbase;
    bf16x8 kv_ = *reinterpret_cast<const bf16x8*>(Kp + t*32 + g*8);
    bf16x8 vv_ = *reinterpret_cast<const bf16x8*>(Vp + t*32 + g*8);
    kf[i] = valid ? kv_ : z8;
    vf[i] = valid ? vv_ : z8;
  }
  bf16x8 qf[4];
  #pragma unroll
  for(int mi = 0; mi < 4; ++mi){
    const int row = mi*16 + col;
    const size_t t = tokbase + (size_t)(h0 + (row >> 3))*128 + (w0 + (row & 7));
    qf[mi] = *reinterpret_cast<const bf16x8*>(Qp + t*32 + g*8);
  }
  // pin K/Q fragments in registers (prevent load sinking into the chunk loop)
  #pragma unroll
  for(int i = 0; i < 10; ++i) asm volatile("" : "+v"(kf[i]));
  #pragma unroll
  for(int mi = 0; mi < 4; ++mi) asm volatile("" : "+v"(qf[mi]));
  // V -> LDS transpose (round-4 verified path)
  #pragma unroll
  for(int i = 0; i < 10; ++i){
    const int kr = i*16 + col;
    #pragma unroll
    for(int e = 0; e < 8; ++e) Vt[g*8 + e][kr] = (u16)vf[i][e];
  }

  const f32x4 fzero = {0.f, 0.f, 0.f, 0.f};
  f32x4 oacc[4][2];
  #pragma unroll
  for(int mi = 0; mi < 4; ++mi){ oacc[mi][0] = fzero; oacc[mi][1] = fzero; }
  const float scale = 0.17677669529663689f;  // 32^-0.5

  #pragma unroll
  for(int ch = 0; ch < 5; ++ch){
    // bias for this chunk (independent -> issues early)
    float4 bv[2][4];
    #pragma unroll
    for(int nf = 0; nf < 2; ++nf)
      #pragma unroll
      for(int mi = 0; mi < 4; ++mi)
        bv[nf][mi] = *reinterpret_cast<const float4*>(
            bias_pk + (size_t)((((head*5 + ch)*2 + nf)*4 + mi)*64 + lane)*4);
    // S^T chunk = K·Q^T : lane holds S^T[kv = ch*32 + nf*16 + g*4 + r][q = mi*16 + col]
    f32x4 st[2][4];
    #pragma unroll
    for(int nf = 0; nf < 2; ++nf)
      #pragma unroll
      for(int mi = 0; mi < 4; ++mi)
        st[nf][mi] = __builtin_amdgcn_mfma_f32_16x16x32_bf16(kf[ch*2 + nf], qf[mi], fzero, 0, 0, 0);
    // P = S^T*scale + bias -> bf16 (integer RNE pack) -> Pl[q][kv_local], one b64 store per tile
    #pragma unroll
    for(int nf = 0; nf < 2; ++nf){
      #pragma unroll
      for(int mi = 0; mi < 4; ++mi){
        const float* bp = reinterpret_cast<const float*>(&bv[nf][mi]);
        const float p0 = fmaf(st[nf][mi][0], scale, bp[0]);
        const float p1 = fmaf(st[nf][mi][1], scale, bp[1]);
        const float p2 = fmaf(st[nf][mi][2], scale, bp[2]);
        const float p3 = fmaf(st[nf][mi][3], scale, bp[3]);
        uint2 pw;
        pw.x = (unsigned)f2bf(p0) | ((unsigned)f2bf(p1) << 16);
        pw.y = (unsigned)f2bf(p2) | ((unsigned)f2bf(p3) << 16);
        *reinterpret_cast<uint2*>(
            reinterpret_cast<char*>(&Pl[0][0]) + (mi*16 + col)*80 + nf*32 + g*8) = pw;
      }
    }
    // P fragments (A-operand): m = q (col), k = kv_local = g*8+e
    bf16x8 pa[4];
    #pragma unroll
    for(int mi = 0; mi < 4; ++mi)
      pa[mi] = *reinterpret_cast<const bf16x8*>(
          reinterpret_cast<const char*>(&Pl[0][0]) + (mi*16 + col)*80 + g*16);
    // V fragments (B-operand): n = d (col), k = kv_local = g*8+e
    bf16x8 vfr[2];
    #pragma unroll
    for(int nf = 0; nf < 2; ++nf)
      vfr[nf] = *reinterpret_cast<const bf16x8*>(&Vt[nf*16 + col][ch*32 + g*8]);
    // O += P·V
    #pragma unroll
    for(int nf = 0; nf < 2; ++nf)
      #pragma unroll
      for(int mi = 0; mi < 4; ++mi)
        oacc[mi][nf] = __builtin_amdgcn_mfma_f32_16x16x32_bf16(pa[mi], vfr[nf], oacc[mi][nf], 0, 0, 0);
  }
  // epilogue: x1 = O + shortcut -> d_out (fp32)
  #pragma unroll
  for(int mi = 0; mi < 4; ++mi){
    #pragma unroll
    for(int nf = 0; nf < 2; ++nf){
      #pragma unroll
      for(int r = 0; r < 4; ++r){
        const int row = mi*16 + g*4 + r;
        const int hh = h0 + (row >> 3), wp = w0 + (row & 7);
        const size_t o = (tokbase + hh*128 + wp)*(size_t)C + head*32 + nf*16 + col;
        out[o] = oacc[mi][nf][r] + x[o];
      }
    }
  }
}

// ---------------- LN2 + FC1 + GELU + FC2 + residual, in-place on d_out ----------------
__global__ __launch_bounds__(512, 4)
void mlp_kernel(float* __restrict__ io,
                const float* __restrict__ g2,
                const float* __restrict__ b2,
                const u16* __restrict__ w1P,
                const float* __restrict__ fb1,
                const u16* __restrict__ w2P,
                const float* __restrict__ fb2){
  __shared__ u16 xn[64][200];
  __shared__ u16 hl[64][200];
  const int tid = threadIdx.x;
  const size_t tok0 = (size_t)blockIdx.x * 64;
  {
    const int trow = tid >> 3;
    const int j = tid & 7;
    const float* xr = io + (tok0 + trow)*C;
    float4 xv[6];
    #pragma unroll
    for(int u = 0; u < 6; ++u)
      xv[u] = *reinterpret_cast<const float4*>(xr + u*32 + j*4);
    float s1 = 0.f, s2 = 0.f;
    #pragma unroll
    for(int u = 0; u < 6; ++u){
      const float* f = reinterpret_cast<const float*>(&xv[u]);
      #pragma unroll
      for(int e = 0; e < 4; ++e){ s1 += f[e]; s2 += f[e]*f[e]; }
    }
    s1 += __shfl_xor(s1, 1, 64); s2 += __shfl_xor(s2, 1, 64);
    s1 += __shfl_xor(s1, 2, 64); s2 += __shfl_xor(s2, 2, 64);
    s1 += __shfl_xor(s1, 4, 64); s2 += __shfl_xor(s2, 4, 64);
    const float mean = s1 * (1.f/192.f);
    const float rstd = rsqrtf(s2*(1.f/192.f) - mean*mean + 1e-5f);
    #pragma unroll
    for(int u = 0; u < 6; ++u){
      const float4 gv = *reinterpret_cast<const float4*>(g2 + u*32 + j*4);
      const float4 bv = *reinterpret_cast<const float4*>(b2 + u*32 + j*4);
      const float* f = reinterpret_cast<const float*>(&xv[u]);
      const float* gp = reinterpret_cast<const float*>(&gv);
      const float* bp = reinterpret_cast<const float*>(&bv);
      u16x4 pk;
      #pragma unroll
      for(int e = 0; e < 4; ++e) pk[e] = f2bf((f[e] - mean)*rstd*gp[e] + bp[e]);
      *reinterpret_cast<u16x4*>(&xn[trow][u*32 + j*4]) = pk;
    }
  }
  __syncthreads();
  const int lane = tid & 63, wave = tid >> 6;
  const int wm = wave >> 2;
  const int wn = wave & 3;
  const int g = lane >> 4, col = lane & 15;
  const f32x4 fzero = {0.f, 0.f, 0.f, 0.f};
  f32x4 acc2[2][3];
  #pragma unroll
  for(int mi = 0; mi < 2; ++mi)
    #pragma unroll
    for(int nf = 0; nf < 3; ++nf) acc2[mi][nf] = fzero;
  #pragma unroll
  for(int hb = 0; hb < 2; ++hb){
    f32x4 acc1[2][3];
    #pragma unroll
    for(int mi = 0; mi < 2; ++mi)
      #pragma unroll
      for(int nf = 0; nf < 3; ++nf) acc1[mi][nf] = fzero;
    #pragma unroll
    for(int ks = 0; ks < 6; ++ks){
      bf16x8 wf[3];
      #pragma unroll
      for(int nf = 0; nf < 3; ++nf)
        wf[nf] = *reinterpret_cast<const bf16x8*>(w1P + ((size_t)(((hb*12 + wn*3 + nf)*6 + ks)*64) + lane)*8);
      bf16x8 a[2];
      #pragma unroll
      for(int mi = 0; mi < 2; ++mi)
        a[mi] = *reinterpret_cast<const bf16x8*>(&xn[wm*32 + mi*16 + col][ks*32 + g*8]);
      #pragma unroll
      for(int nf = 0; nf < 3; ++nf)
        #pragma unroll
        for(int mi = 0; mi < 2; ++mi)
          acc1[mi][nf] = __builtin_amdgcn_mfma_f32_16x16x32_bf16(a[mi], wf[nf], acc1[mi][nf], 0, 0, 0);
    }
    #pragma unroll
    for(int mi = 0; mi < 2; ++mi){
      #pragma unroll
      for(int nf = 0; nf < 3; ++nf){
        const int nl = wn*48 + nf*16 + col;
        const float bb = fb1[hb*192 + nl];
        #pragma unroll
        for(int r = 0; r < 4; ++r){
          const int row = wm*32 + mi*16 + g*4 + r;
          hl[row][nl] = f2bf(gelu(acc1[mi][nf][r] + bb));
        }
      }
    }
    __syncthreads();
    #pragma unroll
    for(int ks = 0; ks < 6; ++ks){
      bf16x8 wf[3];
      #pragma unroll
      for(int nf = 0; nf < 3; ++nf)
        wf[nf] = *reinterpret_cast<const bf16x8*>(w2P + ((size_t)(((wn*3 + nf)*12 + hb*6 + ks)*64) + lane)*8);
      bf16x8 a[2];
      #pragma unroll
      for(int mi = 0; mi < 2; ++mi)
        a[mi] = *reinterpret_cast<const bf16x8*>(&hl[wm*32 + mi*16 + col][ks*32 + g*8]);
      #pragma unroll
      for(int nf = 0; nf < 3; ++nf)
        #pragma unroll
        for(int mi = 0; mi < 2; ++mi)
          acc2[mi][nf] = __builtin_amdgcn_mfma_f32_16x16x32_bf16(a[mi], wf[nf], acc2[mi][nf], 0, 0, 0);
    }
    __syncthreads();
  }
  #pragma unroll
  for(int mi = 0; mi < 2; ++mi){
    #pragma unroll
    for(int nf = 0; nf < 3; ++nf){
      const int n = wn*48 + nf*16 + col;
      const float bb = fb2[n];
      #pragma unroll
      for(int r = 0; r < 4; ++r){
        const int row = wm*32 + mi*16 + g*4 + r;
        const size_t idx = (tok0 + row)*C + n;
        io[idx] = acc2[mi][nf][r] + bb + io[idx];
      }
    }
  }
}

extern "C" void kernel_launch(void* const* d_in, const int* in_sizes, int n_in,
                              void* d_out, int out_size, void* d_ws, size_t ws_size,
                              hipStream_t stream){
  const float* x    = (const float*)d_in[0];
  const int*   rpi  = (const int*)  d_in[2];
  const float* n1g  = (const float*)d_in[3];
  const float* n1b  = (const float*)d_in[4];
  const float* qkvw = (const float*)d_in[5];
  const float* qkvb = (const float*)d_in[6];
  const float* rpb  = (const float*)d_in[7];
  const float* n2g  = (const float*)d_in[8];
  const float* n2b  = (const float*)d_in[9];
  const float* fc1w = (const float*)d_in[10];
  const float* fc1b = (const float*)d_in[11];
  const float* fc2w = (const float*)d_in[12];
  const float* fc2b = (const float*)d_in[13];
  float* out = (float*)d_out;
  char* ws = (char*)d_ws;
  u16*   qkvP    = (u16*)  (ws + 0);
  u16*   fc1P    = (u16*)  (ws + 221184);
  u16*   fc2P    = (u16*)  (ws + 368640);
  float* bias_pk = (float*)(ws + 516096);
  u16*   qkvbuf  = (u16*)  (ws + 1499136);
  if(ws_size < 152494080ull) return;
  prep_kernel<<<dim3(512), dim3(256), 0, stream>>>(qkvw, fc1w, fc2w, rpi, rpb, qkvP, fc1P, fc2P, bias_pk);
  qkv_kernel<<<dim3(4096), dim3(384), 0, stream>>>(x, n1g, n1b, qkvP, qkvb, qkvbuf);
  attn_kernel<<<dim3(2048, 6), dim3(64), 0, stream>>>(qkvbuf, bias_pk, x, out);
  mlp_kernel<<<dim3(2048), dim3(512), 0, stream>>>(out, n2g, n2b, fc1P, fc1b, fc2P, fc2b);
}